// Round 13
// baseline (1043.013 us; speedup 1.0000x reference)
//
#include <hip/hip_runtime.h>

#define NH 50000
#define NT 100000
#define NE 800000
#define MPAD 100096   // 782 * 128

typedef __attribute__((ext_vector_type(8))) short bf16x8;
typedef __attribute__((ext_vector_type(4))) float f32x4;
typedef __attribute__((ext_vector_type(8))) unsigned short u16x8;
typedef __attribute__((ext_vector_type(4))) unsigned int u32x4;

__device__ __forceinline__ unsigned short f2bf(float f){
  unsigned int u = __float_as_uint(f);
  u += 0x7FFFu + ((u >> 16) & 1u);
  return (unsigned short)(u >> 16);
}

__device__ __forceinline__ void fma8(float* acc, float w, uint4 pk){
  acc[0] += w*__uint_as_float(pk.x<<16); acc[1] += w*__uint_as_float(pk.x&0xFFFF0000u);
  acc[2] += w*__uint_as_float(pk.y<<16); acc[3] += w*__uint_as_float(pk.y&0xFFFF0000u);
  acc[4] += w*__uint_as_float(pk.z<<16); acc[5] += w*__uint_as_float(pk.z&0xFFFF0000u);
  acc[6] += w*__uint_as_float(pk.w<<16); acc[7] += w*__uint_as_float(pk.w&0xFFFF0000u);
}

// async 16B global -> LDS (linear dest = wave-uniform base + lane*16)
__device__ __forceinline__ void gl2lds16(const unsigned short* g, unsigned short* l){
  __builtin_amdgcn_global_load_lds(
      (const __attribute__((address_space(1))) void*)g,
      (__attribute__((address_space(3))) void*)l, 16, 0, 0);
}

// ================= F1: cvt || hist || wt || prep (independent, fused) =================
__global__ __launch_bounds__(256) void k_fuse1(
      const float* __restrict__ tail_f, unsigned short* __restrict__ A_bf,
      const int* __restrict__ head_ind, int* __restrict__ cnt,
      const float* __restrict__ W, unsigned short* __restrict__ Wt,
      const float* __restrict__ W_e, const float* __restrict__ edge_emb,
      const float* __restrict__ a_l, const float* __restrict__ a_r,
      const float* __restrict__ a_e,
      unsigned short* __restrict__ wlr_t, float* __restrict__ h_e){
  __shared__ float s_al[512], s_ar[512], s_ae[512], s_wef[512];
  int b = blockIdx.x, t = threadIdx.x;
  if (b < 12500){
    // ---- cvt: tail_feature fp32 -> bf16 [NT][256]
    size_t g = (size_t)b*256 + t;
    const float* src = tail_f + g*8;
    float4 v0 = *(const float4*)(src);
    float4 v1 = *(const float4*)(src + 4);
    u16x8 s;
    s[0]=f2bf(v0.x); s[1]=f2bf(v0.y); s[2]=f2bf(v0.z); s[3]=f2bf(v0.w);
    s[4]=f2bf(v1.x); s[5]=f2bf(v1.y); s[6]=f2bf(v1.z); s[7]=f2bf(v1.w);
    *(u16x8*)(A_bf + g*8) = s;
  } else if (b < 15625){
    // ---- hist
    int e = (b-12500)*256 + t;
    atomicAdd(&cnt[head_ind[e]], 1);
  } else if (b < 16137){
    // ---- wt: W transposed bf16 [512][256]
    int n = b - 15625, k = t;
    Wt[n*256+k] = f2bf(W[k*512+n]);
  } else {
    // ---- prep
    for (int i=t;i<512;i+=256){ s_al[i]=a_l[i]; s_ar[i]=a_r[i]; s_ae[i]=a_e[i]; }
    __syncthreads();
    { int k = t;
      for (int h=0;h<8;h++){
        float accl=0.f, accr=0.f;
        for (int d=0; d<64; d++){
          float w = W[k*512 + h*64 + d];
          accl += w*s_al[h*64+d];
          accr += w*s_ar[h*64+d];
        }
        wlr_t[h*256 + k]     = f2bf(accl);
        wlr_t[(8+h)*256 + k] = f2bf(accr);
      }
    }
    if (t<64){
      for (int h=0;h<8;h++){
        float acc=0.f;
        for (int f=0; f<64; f++) acc += W_e[t*512 + h*64 + f]*s_ae[h*64+f];
        s_wef[t*8+h]=acc;
      }
    }
    __syncthreads();
    if (t<40){
      int ty=t>>3, h=t&7;
      float acc=0.f;
      for (int k2=0;k2<64;k2++) acc += edge_emb[ty*64+k2]*s_wef[k2*8+h];
      h_e[t]=acc;
    }
  }
}

// ================= F2: scan(block 0) || gemm || hl, 40 KB LDS union ==========
__device__ __forceinline__ void scan_body(int* s,
      const int* __restrict__ cnt, int* __restrict__ offs, int* __restrict__ cur){
  int t = threadIdx.x;
  int base_i = t*196;                       // 256*196 = 50176 >= NH
  int sum = 0;
  for (int j=0;j<196;j++){ int g=base_i+j; sum += (g<NH)? cnt[g] : 0; }
  s[t] = sum; __syncthreads();
  int v = sum;
  for (int off=1; off<256; off<<=1){
    int u = (t>=off)? s[t-off] : 0; __syncthreads();
    s[t] += u; __syncthreads();
  }
  int run = s[t] - v;                       // exclusive prefix
  for (int j=0;j<196;j++){
    int g = base_i + j;
    if (g < NH){ int c = cnt[g]; offs[g]=run; cur[g]=run; run += c; }
  }
  if (t==255) offs[NH] = s[t];              // inclusive total = E
}

__device__ __forceinline__ void gemm3_body(unsigned short* smem, int bid,
      const unsigned short* __restrict__ A_bf, const unsigned short* __restrict__ Wt,
      const float* __restrict__ a_r_g, unsigned short* __restrict__ Cout,
      float* __restrict__ h_r){
  unsigned short* As0 = smem;          // 16 KB
  unsigned short* As1 = smem + 8192;   // 16 KB
  int t = threadIdx.x;
  int wave = t>>6, lane = t&63;
  int lr = lane & 15, lq = lane >> 4;

  // XCD-bijective + panel-grouped decode: 3128 = 8*391
  int wg  = (bid & 7)*391 + (bid >> 3);
  int m0 = (wg >> 2)*128;
  int n0 = (wg & 3)*128;
  int wm = (wave>>1)*64, wn = (wave&1)*64;

  f32x4 acc[4][4];
#pragma unroll
  for (int mf=0;mf<4;mf++)
#pragma unroll
    for (int nf=0;nf<4;nf++) acc[mf][nf] = (f32x4){0.f,0.f,0.f,0.f};

  bf16x8 b0[8], b1[8], b2[8], b3[8];

#define STAGEA(dst, kt) do { \
    _Pragma("unroll") \
    for (int i=0;i<4;i++){ \
      int v = wave*256 + i*64 + lane; \
      int row = v>>3, un = (v&7) ^ (row&7); \
      gl2lds16(A_bf + (size_t)(m0+row)*256 + (kt)*64 + un*8, \
               &(dst)[(wave*256 + i*64)*8]); \
    } } while(0)

#define LOADB(kt, bb) do { \
    _Pragma("unroll") \
    for (int ks=0;ks<2;ks++) \
      _Pragma("unroll") \
      for (int nf=0;nf<4;nf++){ \
        int c = wn + nf*16 + lr; \
        (bb)[ks*4+nf] = *(const bf16x8*)(Wt + (size_t)(n0+c)*256 + ((kt)*8+ks*4+lq)*8); \
      } } while(0)

#define COMPUTE(Asb, bb) do { \
    _Pragma("unroll") \
    for (int ks=0;ks<2;ks++){ \
      bf16x8 af[4]; \
      _Pragma("unroll") \
      for (int mf=0;mf<4;mf++){ \
        int r = wm + mf*16 + lr; \
        int u = (ks*4 + lq) ^ (r&7); \
        af[mf] = *(const bf16x8*)((const char*)(Asb) + r*128 + u*16); \
      } \
      _Pragma("unroll") \
      for (int mf=0;mf<4;mf++) \
        _Pragma("unroll") \
        for (int nf=0;nf<4;nf++) \
          acc[mf][nf] = __builtin_amdgcn_mfma_f32_16x16x32_bf16(af[mf], (bb)[ks*4+nf], acc[mf][nf], 0,0,0); \
    } } while(0)

#define WAITV(N) asm volatile("s_waitcnt vmcnt(" #N ")" ::: "memory")
#define RBAR() do { __builtin_amdgcn_s_barrier(); __builtin_amdgcn_sched_barrier(0); } while(0)

  STAGEA(As0, 0); LOADB(0, b0);
  STAGEA(As1, 1); LOADB(1, b1);
  WAITV(20); RBAR();
  COMPUTE(As0, b0);
  RBAR();
  STAGEA(As0, 2); LOADB(2, b2);
  WAITV(20); RBAR();
  COMPUTE(As1, b1);
  RBAR();
  STAGEA(As1, 3); LOADB(3, b3);
  WAITV(20); RBAR();
  COMPUTE(As0, b2);
  WAITV(8);  RBAR();
  COMPUTE(As1, b3);
#undef STAGEA
#undef LOADB
#undef COMPUTE
#undef WAITV
#undef RBAR

  // epilogue A: h_r[row, head] = sum_d a_r[h,d]*C_fp32[row, h*64+d]
  {
    int h = (n0 + wn) >> 6;
    float w[4];
#pragma unroll
    for (int nf=0;nf<4;nf++) w[nf] = a_r_g[h*64 + nf*16 + lr];
#pragma unroll
    for (int mf=0;mf<4;mf++)
#pragma unroll
      for (int j=0;j<4;j++){
        float s = acc[mf][0][j]*w[0] + acc[mf][1][j]*w[1]
                + acc[mf][2][j]*w[2] + acc[mf][3][j]*w[3];
        s += __shfl_xor(s, 1); s += __shfl_xor(s, 2);
        s += __shfl_xor(s, 4); s += __shfl_xor(s, 8);
        int gr = m0 + wm + mf*16 + lq*4 + j;
        if (lr == 0 && gr < NT) h_r[(size_t)gr*8 + h] = s;
      }
  }

  // epilogue B: coalesced C store via LDS (reuse smem as [128][256B], XOR bits 5-6)
  __syncthreads();
  unsigned short* Cs = smem;
#pragma unroll
  for (int mf=0;mf<4;mf++)
#pragma unroll
    for (int nf=0;nf<4;nf++)
#pragma unroll
      for (int j=0;j<4;j++){
        int row = wm + mf*16 + lq*4 + j;
        int cb  = (wn + nf*16 + lr)*2;
        *(unsigned short*)((char*)Cs + row*256 + (cb ^ ((row&12)<<3))) = f2bf(acc[mf][nf][j]);
      }
  __syncthreads();
#pragma unroll
  for (int i=0;i<8;i++){
    int v = i*256 + t;          // 16B unit id, 0..2047
    int row = v>>4, u = v&15;
    u32x4 val = *(const u32x4*)((const char*)Cs + row*256 + ((u*16) ^ ((row&12)<<3)));
    *(u32x4*)(Cout + (size_t)(m0+row)*512 + n0 + u*8) = val;
  }
}

__device__ __forceinline__ void hl_body(unsigned short* As, unsigned short* Bs, int bid,
      const float* __restrict__ head_f, const unsigned short* __restrict__ wlr_t,
      float* __restrict__ h_l){
  int t = threadIdx.x;
  int wave = t>>6, lane = t&63;
  int lr = lane&15, lq = lane>>4;
  long r0 = (long)bid*256;

#pragma unroll
  for (int i=0;i<2;i++){
    int q = i*256 + t;
    int c = q>>5, un = q&31;
    float4 v = *(const float4*)(wlr_t + c*256 + un*8);
    int u = un ^ (c&7);
    *(float4*)((char*)Bs + c*512 + u*16) = v;
  }

  f32x4 acc[4];
#pragma unroll
  for (int mf=0;mf<4;mf++) acc[mf]=(f32x4){0.f,0.f,0.f,0.f};

  for (int kt=0; kt<4; kt++){
    __syncthreads();
#pragma unroll
    for (int i=0;i<16;i++){
      int q = i*256+t;
      int row = q>>4, cg = q&15;
      long gr = r0 + row;
      float4 v = make_float4(0.f,0.f,0.f,0.f);
      if (gr < NH) v = *(const float4*)(head_f + gr*256 + kt*64 + cg*4);
      int u = (cg>>1) ^ (row&7);
      ushort4 sv;
      sv.x=f2bf(v.x); sv.y=f2bf(v.y); sv.z=f2bf(v.z); sv.w=f2bf(v.w);
      *(ushort4*)((char*)As + row*128 + u*16 + (cg&1)*8) = sv;
    }
    __syncthreads();
#pragma unroll
    for (int ks=0;ks<2;ks++){
      int un = kt*8 + ks*4 + lq;
      int cu = un ^ (lr&7);
      bf16x8 bfr = *(const bf16x8*)((const char*)Bs + lr*512 + cu*16);
#pragma unroll
      for (int mf=0;mf<4;mf++){
        int r = wave*64 + mf*16 + lr;
        int u = (ks*4+lq) ^ (r&7);
        bf16x8 afr = *(const bf16x8*)((const char*)As + r*128 + u*16);
        acc[mf] = __builtin_amdgcn_mfma_f32_16x16x32_bf16(afr, bfr, acc[mf], 0,0,0);
      }
    }
  }
#pragma unroll
  for (int mf=0;mf<4;mf++)
#pragma unroll
    for (int j=0;j<4;j++){
      long grow = r0 + wave*64 + mf*16 + lq*4 + j;
      if (grow < NH && lr < 8) h_l[grow*8+lr] = acc[mf][j];
    }
}

__global__ __launch_bounds__(256) void k_fuse2(
      const unsigned short* __restrict__ A_bf, const unsigned short* __restrict__ Wt,
      const float* __restrict__ a_r_g, unsigned short* __restrict__ Cout,
      float* __restrict__ h_r,
      const float* __restrict__ head_f, const unsigned short* __restrict__ wlr_t,
      float* __restrict__ h_l,
      const int* __restrict__ cnt, int* __restrict__ offs, int* __restrict__ cur){
  __shared__ __align__(16) unsigned short smem[20480];   // 40 KB union
  if (blockIdx.x == 0)
    scan_body((int*)smem, cnt, offs, cur);
  else if (blockIdx.x <= 3128)
    gemm3_body(smem, blockIdx.x - 1, A_bf, Wt, a_r_g, Cout, h_r);
  else
    hl_body(smem, smem + 16384, blockIdx.x - 3129, head_f, wlr_t, h_l);
}

// ---------------- D1: logits + CSR scatter ----------------
__global__ void k_logit2(const int* __restrict__ head_ind, const int* __restrict__ tail_ind,
                         const int* __restrict__ tmp_edge,
                         const float* __restrict__ h_l, const float* __restrict__ h_r,
                         const float* __restrict__ h_e,
                         int* __restrict__ cur,
                         float* __restrict__ att_csr,
                         int* __restrict__ edge_of, int* __restrict__ tail_s){
  int g = blockIdx.x*256 + threadIdx.x;   // NE*8 threads exactly
  int e = g>>3, h = g&7, l = threadIdx.x&63;
  int hd = head_ind[e], tl = tail_ind[e], ty = tmp_edge[e];
  float v = h_l[hd*8+h] + h_r[(size_t)tl*8+h] + h_e[ty*8+h];
  v = v > 0.f ? v : 0.2f*v;
  int p = 0;
  if (h==0) p = atomicAdd(&cur[hd], 1);
  p = __shfl(p, l & ~7);
  att_csr[p*8+h] = v;
  if (h==0){ edge_of[p]=e; tail_s[p]=tl; }
}

// ---------------- E: persistent-wave softmax + aggregation + att write ----------------
__global__ __launch_bounds__(256) void k_agg4(const int* __restrict__ offs,
      const int* __restrict__ edge_of, const int* __restrict__ tail_s,
      const float* __restrict__ att_csr,
      const unsigned short* __restrict__ h_tail,
      int* __restrict__ wctr,
      float* __restrict__ att, float* __restrict__ out){
  int t = threadIdx.x;
  int l = t & 63;
  int h = l & 7, hq = l >> 3;

  while (true){
    int i;
    if (l == 0) i = atomicAdd(wctr, 1);
    i = __shfl(i, 0);
    if (i >= NH) break;

    int s0 = offs[i];
    int deg = offs[i+1] - s0;

    // softmax stats (contiguous att_csr reads)
    float m = -1e30f;
    for (int q = hq; q < deg; q += 8) m = fmaxf(m, att_csr[(s0+q)*8 + h]);
    m = fmaxf(m, __shfl_xor(m, 8));
    m = fmaxf(m, __shfl_xor(m, 16));
    m = fmaxf(m, __shfl_xor(m, 32));
    float sum = 0.f;
    for (int q = hq; q < deg; q += 8) sum += __expf(att_csr[(s0+q)*8 + h] - m);
    sum += __shfl_xor(sum, 8); sum += __shfl_xor(sum, 16); sum += __shfl_xor(sum, 32);
    float r = (deg > 0) ? 1.f/sum : 0.f;

    float mh = __shfl(m, hq), rh = __shfl(r, hq);
    bool wlane = (l & 7) == 0;
    float acc[8];
#pragma unroll
    for (int c=0;c<8;c++) acc[c]=0.f;
    int j = 0;
    for (; j+4 <= deg; j += 4){
      int p0=s0+j, p1=p0+1, p2=p0+2, p3=p0+3;
      int t0=tail_s[p0], t1=tail_s[p1], t2=tail_s[p2], t3=tail_s[p3];
      float a0=att_csr[p0*8+hq], a1=att_csr[p1*8+hq];
      float a2=att_csr[p2*8+hq], a3=att_csr[p3*8+hq];
      uint4 r0 = *(const uint4*)(h_tail + (size_t)t0*512 + l*8);
      uint4 r1 = *(const uint4*)(h_tail + (size_t)t1*512 + l*8);
      uint4 r2 = *(const uint4*)(h_tail + (size_t)t2*512 + l*8);
      uint4 r3 = *(const uint4*)(h_tail + (size_t)t3*512 + l*8);
      float w0=__expf(a0-mh)*rh, w1=__expf(a1-mh)*rh;
      float w2=__expf(a2-mh)*rh, w3=__expf(a3-mh)*rh;
      if (wlane){
        __builtin_nontemporal_store(w0, &att[(size_t)edge_of[p0]*8 + hq]);
        __builtin_nontemporal_store(w1, &att[(size_t)edge_of[p1]*8 + hq]);
        __builtin_nontemporal_store(w2, &att[(size_t)edge_of[p2]*8 + hq]);
        __builtin_nontemporal_store(w3, &att[(size_t)edge_of[p3]*8 + hq]);
      }
      fma8(acc, w0, r0);
      fma8(acc, w1, r1);
      fma8(acc, w2, r2);
      fma8(acc, w3, r3);
    }
    for (; j < deg; j++){
      int p0 = s0+j;
      int t0 = tail_s[p0];
      float a0 = att_csr[p0*8 + hq];
      uint4 r0 = *(const uint4*)(h_tail + (size_t)t0*512 + l*8);
      float w0 = __expf(a0 - mh) * rh;
      if (wlane) __builtin_nontemporal_store(w0, &att[(size_t)edge_of[p0]*8 + hq]);
      fma8(acc, w0, r0);
    }
    float* o = out + (size_t)i*512 + l*8;
    f32x4 v0 = {acc[0],acc[1],acc[2],acc[3]};
    f32x4 v1 = {acc[4],acc[5],acc[6],acc[7]};
    __builtin_nontemporal_store(v0, (f32x4*)o);
    __builtin_nontemporal_store(v1, (f32x4*)(o+4));
  }
}

extern "C" void kernel_launch(void* const* d_in, const int* in_sizes, int n_in,
                              void* d_out, int out_size, void* d_ws, size_t ws_size,
                              hipStream_t stream) {
  const float* head_f   = (const float*)d_in[0];
  const float* tail_f   = (const float*)d_in[1];
  const int*   head_ind = (const int*)d_in[2];
  const int*   tail_ind = (const int*)d_in[3];
  const int*   tmp_edge = (const int*)d_in[4];
  const float* edge_emb = (const float*)d_in[5];
  const float* W        = (const float*)d_in[6];
  const float* W_e      = (const float*)d_in[7];
  const float* a_l      = (const float*)d_in[8];
  const float* a_r      = (const float*)d_in[9];
  const float* a_e      = (const float*)d_in[10];

  float* out = (float*)d_out;
  float* att = out + (size_t)NH*512;
  // A_bf scratch lives in the `out` region (51.3 MB <= 102 MB); k_agg4 fully
  // overwrites `out` afterwards, so this is deterministic and ws stays small.
  unsigned short* A_bf = (unsigned short*)d_out;

  char* ws = (char*)d_ws;
  auto alloc = [&](size_t bytes)->char*{ char* p = ws; ws += (bytes+511)&~(size_t)511; return p; };
  unsigned short* Wt    = (unsigned short*)alloc((size_t)512*256*2);
  unsigned short* wlr_t = (unsigned short*)alloc((size_t)16*256*2);
  float* h_e            = (float*)alloc(512);
  float* h_l            = (float*)alloc((size_t)NH*8*4);
  float* h_r            = (float*)alloc((size_t)NT*8*4);
  unsigned short* h_tail= (unsigned short*)alloc((size_t)MPAD*512*2);
  int* cnt              = (int*)alloc((size_t)(NH+1)*4);   // [NH] = work-steal ctr
  int* offs             = (int*)alloc((size_t)(NH+1)*4);
  int* cur              = (int*)alloc((size_t)NH*4);
  int* edge_of          = (int*)alloc((size_t)NE*4);
  int* tail_s           = (int*)alloc((size_t)NE*4);
  float* att_csr        = (float*)alloc((size_t)NE*8*4);
  int* wctr             = cnt + NH;

  hipMemsetAsync(cnt, 0, (size_t)(NH+1)*4, stream);
  k_fuse1<<<16138,256,0,stream>>>(tail_f, A_bf, head_ind, cnt, W, Wt,
                                  W_e, edge_emb, a_l, a_r, a_e, wlr_t, h_e);
  k_fuse2<<<1+3128+196,256,0,stream>>>(A_bf, Wt, a_r, h_tail, h_r,
                                       head_f, wlr_t, h_l, cnt, offs, cur);
  k_logit2<<<NE*8/256,256,0,stream>>>(head_ind, tail_ind, tmp_edge, h_l, h_r, h_e,
                                      cur, att_csr, edge_of, tail_s);
  k_agg4<<<2048,256,0,stream>>>(offs, edge_of, tail_s, att_csr, h_tail, wctr, att, out);
}

// Round 14
// 486.352 us; speedup vs baseline: 2.1446x; 2.1446x over previous
//
#include <hip/hip_runtime.h>

#define NH 50000
#define NT 100000
#define NE 800000
#define MPAD 100096   // 782 * 128

typedef __attribute__((ext_vector_type(8))) short bf16x8;
typedef __attribute__((ext_vector_type(4))) float f32x4;
typedef __attribute__((ext_vector_type(8))) unsigned short u16x8;
typedef __attribute__((ext_vector_type(4))) unsigned int u32x4;

__device__ __forceinline__ unsigned short f2bf(float f){
  unsigned int u = __float_as_uint(f);
  u += 0x7FFFu + ((u >> 16) & 1u);
  return (unsigned short)(u >> 16);
}

__device__ __forceinline__ void fma8(float* acc, float w, uint4 pk){
  acc[0] += w*__uint_as_float(pk.x<<16); acc[1] += w*__uint_as_float(pk.x&0xFFFF0000u);
  acc[2] += w*__uint_as_float(pk.y<<16); acc[3] += w*__uint_as_float(pk.y&0xFFFF0000u);
  acc[4] += w*__uint_as_float(pk.z<<16); acc[5] += w*__uint_as_float(pk.z&0xFFFF0000u);
  acc[6] += w*__uint_as_float(pk.w<<16); acc[7] += w*__uint_as_float(pk.w&0xFFFF0000u);
}

// async 16B global -> LDS (linear dest = wave-uniform base + lane*16)
__device__ __forceinline__ void gl2lds16(const unsigned short* g, unsigned short* l){
  __builtin_amdgcn_global_load_lds(
      (const __attribute__((address_space(1))) void*)g,
      (__attribute__((address_space(3))) void*)l, 16, 0, 0);
}

// ================= F1: cvt || hist || wt || prep (independent, fused) =================
__global__ __launch_bounds__(256) void k_fuse1(
      const float* __restrict__ tail_f, unsigned short* __restrict__ A_bf,
      const int* __restrict__ head_ind, int* __restrict__ cnt,
      const float* __restrict__ W, unsigned short* __restrict__ Wt,
      const float* __restrict__ W_e, const float* __restrict__ edge_emb,
      const float* __restrict__ a_l, const float* __restrict__ a_r,
      const float* __restrict__ a_e,
      unsigned short* __restrict__ wlr_t, float* __restrict__ h_e){
  __shared__ float s_al[512], s_ar[512], s_ae[512], s_wef[512];
  int b = blockIdx.x, t = threadIdx.x;
  if (b < 12500){
    // ---- cvt: tail_feature fp32 -> bf16 [NT][256]
    size_t g = (size_t)b*256 + t;
    const float* src = tail_f + g*8;
    float4 v0 = *(const float4*)(src);
    float4 v1 = *(const float4*)(src + 4);
    u16x8 s;
    s[0]=f2bf(v0.x); s[1]=f2bf(v0.y); s[2]=f2bf(v0.z); s[3]=f2bf(v0.w);
    s[4]=f2bf(v1.x); s[5]=f2bf(v1.y); s[6]=f2bf(v1.z); s[7]=f2bf(v1.w);
    *(u16x8*)(A_bf + g*8) = s;
  } else if (b < 15625){
    // ---- hist
    int e = (b-12500)*256 + t;
    atomicAdd(&cnt[head_ind[e]], 1);
  } else if (b < 16137){
    // ---- wt: W transposed bf16 [512][256]
    int n = b - 15625, k = t;
    Wt[n*256+k] = f2bf(W[k*512+n]);
  } else {
    // ---- prep
    for (int i=t;i<512;i+=256){ s_al[i]=a_l[i]; s_ar[i]=a_r[i]; s_ae[i]=a_e[i]; }
    __syncthreads();
    { int k = t;
      for (int h=0;h<8;h++){
        float accl=0.f, accr=0.f;
        for (int d=0; d<64; d++){
          float w = W[k*512 + h*64 + d];
          accl += w*s_al[h*64+d];
          accr += w*s_ar[h*64+d];
        }
        wlr_t[h*256 + k]     = f2bf(accl);
        wlr_t[(8+h)*256 + k] = f2bf(accr);
      }
    }
    if (t<64){
      for (int h=0;h<8;h++){
        float acc=0.f;
        for (int f=0; f<64; f++) acc += W_e[t*512 + h*64 + f]*s_ae[h*64+f];
        s_wef[t*8+h]=acc;
      }
    }
    __syncthreads();
    if (t<40){
      int ty=t>>3, h=t&7;
      float acc=0.f;
      for (int k2=0;k2<64;k2++) acc += edge_emb[ty*64+k2]*s_wef[k2*8+h];
      h_e[t]=acc;
    }
  }
}

// ================= F2: scan(block 0) || gemm || hl, 40 KB LDS union ==========
__device__ __forceinline__ void scan_body(int* s,
      const int* __restrict__ cnt, int* __restrict__ offs, int* __restrict__ cur){
  int t = threadIdx.x;
  int base_i = t*196;                       // 256*196 = 50176 >= NH
  int sum = 0;
  for (int j=0;j<196;j++){ int g=base_i+j; sum += (g<NH)? cnt[g] : 0; }
  s[t] = sum; __syncthreads();
  int v = sum;
  for (int off=1; off<256; off<<=1){
    int u = (t>=off)? s[t-off] : 0; __syncthreads();
    s[t] += u; __syncthreads();
  }
  int run = s[t] - v;                       // exclusive prefix
  for (int j=0;j<196;j++){
    int g = base_i + j;
    if (g < NH){ int c = cnt[g]; offs[g]=run; cur[g]=run; run += c; }
  }
  if (t==255) offs[NH] = s[t];              // inclusive total = E
}

__device__ __forceinline__ void gemm3_body(unsigned short* smem, int bid,
      const unsigned short* __restrict__ A_bf, const unsigned short* __restrict__ Wt,
      const float* __restrict__ a_r_g, unsigned short* __restrict__ Cout,
      float* __restrict__ h_r){
  unsigned short* As0 = smem;          // 16 KB
  unsigned short* As1 = smem + 8192;   // 16 KB
  int t = threadIdx.x;
  int wave = t>>6, lane = t&63;
  int lr = lane & 15, lq = lane >> 4;

  // XCD-bijective + panel-grouped decode: 3128 = 8*391
  int wg  = (bid & 7)*391 + (bid >> 3);
  int m0 = (wg >> 2)*128;
  int n0 = (wg & 3)*128;
  int wm = (wave>>1)*64, wn = (wave&1)*64;

  f32x4 acc[4][4];
#pragma unroll
  for (int mf=0;mf<4;mf++)
#pragma unroll
    for (int nf=0;nf<4;nf++) acc[mf][nf] = (f32x4){0.f,0.f,0.f,0.f};

  bf16x8 b0[8], b1[8], b2[8], b3[8];

#define STAGEA(dst, kt) do { \
    _Pragma("unroll") \
    for (int i=0;i<4;i++){ \
      int v = wave*256 + i*64 + lane; \
      int row = v>>3, un = (v&7) ^ (row&7); \
      gl2lds16(A_bf + (size_t)(m0+row)*256 + (kt)*64 + un*8, \
               &(dst)[(wave*256 + i*64)*8]); \
    } } while(0)

#define LOADB(kt, bb) do { \
    _Pragma("unroll") \
    for (int ks=0;ks<2;ks++) \
      _Pragma("unroll") \
      for (int nf=0;nf<4;nf++){ \
        int c = wn + nf*16 + lr; \
        (bb)[ks*4+nf] = *(const bf16x8*)(Wt + (size_t)(n0+c)*256 + ((kt)*8+ks*4+lq)*8); \
      } } while(0)

#define COMPUTE(Asb, bb) do { \
    _Pragma("unroll") \
    for (int ks=0;ks<2;ks++){ \
      bf16x8 af[4]; \
      _Pragma("unroll") \
      for (int mf=0;mf<4;mf++){ \
        int r = wm + mf*16 + lr; \
        int u = (ks*4 + lq) ^ (r&7); \
        af[mf] = *(const bf16x8*)((const char*)(Asb) + r*128 + u*16); \
      } \
      _Pragma("unroll") \
      for (int mf=0;mf<4;mf++) \
        _Pragma("unroll") \
        for (int nf=0;nf<4;nf++) \
          acc[mf][nf] = __builtin_amdgcn_mfma_f32_16x16x32_bf16(af[mf], (bb)[ks*4+nf], acc[mf][nf], 0,0,0); \
    } } while(0)

#define WAITV(N) asm volatile("s_waitcnt vmcnt(" #N ")" ::: "memory")
#define RBAR() do { __builtin_amdgcn_s_barrier(); __builtin_amdgcn_sched_barrier(0); } while(0)

  STAGEA(As0, 0); LOADB(0, b0);
  STAGEA(As1, 1); LOADB(1, b1);
  WAITV(20); RBAR();
  COMPUTE(As0, b0);
  RBAR();
  STAGEA(As0, 2); LOADB(2, b2);
  WAITV(20); RBAR();
  COMPUTE(As1, b1);
  RBAR();
  STAGEA(As1, 3); LOADB(3, b3);
  WAITV(20); RBAR();
  COMPUTE(As0, b2);
  WAITV(8);  RBAR();
  COMPUTE(As1, b3);
#undef STAGEA
#undef LOADB
#undef COMPUTE
#undef WAITV
#undef RBAR

  // epilogue A: h_r[row, head] = sum_d a_r[h,d]*C_fp32[row, h*64+d]
  {
    int h = (n0 + wn) >> 6;
    float w[4];
#pragma unroll
    for (int nf=0;nf<4;nf++) w[nf] = a_r_g[h*64 + nf*16 + lr];
#pragma unroll
    for (int mf=0;mf<4;mf++)
#pragma unroll
      for (int j=0;j<4;j++){
        float s = acc[mf][0][j]*w[0] + acc[mf][1][j]*w[1]
                + acc[mf][2][j]*w[2] + acc[mf][3][j]*w[3];
        s += __shfl_xor(s, 1); s += __shfl_xor(s, 2);
        s += __shfl_xor(s, 4); s += __shfl_xor(s, 8);
        int gr = m0 + wm + mf*16 + lq*4 + j;
        if (lr == 0 && gr < NT) h_r[(size_t)gr*8 + h] = s;
      }
  }

  // epilogue B: coalesced C store via LDS (reuse smem as [128][256B], XOR bits 5-6)
  __syncthreads();
  unsigned short* Cs = smem;
#pragma unroll
  for (int mf=0;mf<4;mf++)
#pragma unroll
    for (int nf=0;nf<4;nf++)
#pragma unroll
      for (int j=0;j<4;j++){
        int row = wm + mf*16 + lq*4 + j;
        int cb  = (wn + nf*16 + lr)*2;
        *(unsigned short*)((char*)Cs + row*256 + (cb ^ ((row&12)<<3))) = f2bf(acc[mf][nf][j]);
      }
  __syncthreads();
#pragma unroll
  for (int i=0;i<8;i++){
    int v = i*256 + t;          // 16B unit id, 0..2047
    int row = v>>4, u = v&15;
    u32x4 val = *(const u32x4*)((const char*)Cs + row*256 + ((u*16) ^ ((row&12)<<3)));
    *(u32x4*)(Cout + (size_t)(m0+row)*512 + n0 + u*8) = val;
  }
}

__device__ __forceinline__ void hl_body(unsigned short* As, unsigned short* Bs, int bid,
      const float* __restrict__ head_f, const unsigned short* __restrict__ wlr_t,
      float* __restrict__ h_l){
  int t = threadIdx.x;
  int wave = t>>6, lane = t&63;
  int lr = lane&15, lq = lane>>4;
  long r0 = (long)bid*256;

#pragma unroll
  for (int i=0;i<2;i++){
    int q = i*256 + t;
    int c = q>>5, un = q&31;
    float4 v = *(const float4*)(wlr_t + c*256 + un*8);
    int u = un ^ (c&7);
    *(float4*)((char*)Bs + c*512 + u*16) = v;
  }

  f32x4 acc[4];
#pragma unroll
  for (int mf=0;mf<4;mf++) acc[mf]=(f32x4){0.f,0.f,0.f,0.f};

  for (int kt=0; kt<4; kt++){
    __syncthreads();
#pragma unroll
    for (int i=0;i<16;i++){
      int q = i*256+t;
      int row = q>>4, cg = q&15;
      long gr = r0 + row;
      float4 v = make_float4(0.f,0.f,0.f,0.f);
      if (gr < NH) v = *(const float4*)(head_f + gr*256 + kt*64 + cg*4);
      int u = (cg>>1) ^ (row&7);
      ushort4 sv;
      sv.x=f2bf(v.x); sv.y=f2bf(v.y); sv.z=f2bf(v.z); sv.w=f2bf(v.w);
      *(ushort4*)((char*)As + row*128 + u*16 + (cg&1)*8) = sv;
    }
    __syncthreads();
#pragma unroll
    for (int ks=0;ks<2;ks++){
      int un = kt*8 + ks*4 + lq;
      int cu = un ^ (lr&7);
      bf16x8 bfr = *(const bf16x8*)((const char*)Bs + lr*512 + cu*16);
#pragma unroll
      for (int mf=0;mf<4;mf++){
        int r = wave*64 + mf*16 + lr;
        int u = (ks*4+lq) ^ (r&7);
        bf16x8 afr = *(const bf16x8*)((const char*)As + r*128 + u*16);
        acc[mf] = __builtin_amdgcn_mfma_f32_16x16x32_bf16(afr, bfr, acc[mf], 0,0,0);
      }
    }
  }
#pragma unroll
  for (int mf=0;mf<4;mf++)
#pragma unroll
    for (int j=0;j<4;j++){
      long grow = r0 + wave*64 + mf*16 + lq*4 + j;
      if (grow < NH && lr < 8) h_l[grow*8+lr] = acc[mf][j];
    }
}

__global__ __launch_bounds__(256) void k_fuse2(
      const unsigned short* __restrict__ A_bf, const unsigned short* __restrict__ Wt,
      const float* __restrict__ a_r_g, unsigned short* __restrict__ Cout,
      float* __restrict__ h_r,
      const float* __restrict__ head_f, const unsigned short* __restrict__ wlr_t,
      float* __restrict__ h_l,
      const int* __restrict__ cnt, int* __restrict__ offs, int* __restrict__ cur){
  __shared__ __align__(16) unsigned short smem[20480];   // 40 KB union
  if (blockIdx.x == 0)
    scan_body((int*)smem, cnt, offs, cur);
  else if (blockIdx.x <= 3128)
    gemm3_body(smem, blockIdx.x - 1, A_bf, Wt, a_r_g, Cout, h_r);
  else
    hl_body(smem, smem + 16384, blockIdx.x - 3129, head_f, wlr_t, h_l);
}

// ---------------- D1: logits + CSR scatter ----------------
__global__ void k_logit2(const int* __restrict__ head_ind, const int* __restrict__ tail_ind,
                         const int* __restrict__ tmp_edge,
                         const float* __restrict__ h_l, const float* __restrict__ h_r,
                         const float* __restrict__ h_e,
                         int* __restrict__ cur,
                         float* __restrict__ att_csr,
                         int* __restrict__ edge_of, int* __restrict__ tail_s){
  int g = blockIdx.x*256 + threadIdx.x;   // NE*8 threads exactly
  int e = g>>3, h = g&7, l = threadIdx.x&63;
  int hd = head_ind[e], tl = tail_ind[e], ty = tmp_edge[e];
  float v = h_l[hd*8+h] + h_r[(size_t)tl*8+h] + h_e[ty*8+h];
  v = v > 0.f ? v : 0.2f*v;
  int p = 0;
  if (h==0) p = atomicAdd(&cur[hd], 1);
  p = __shfl(p, l & ~7);
  att_csr[p*8+h] = v;
  if (h==0){ edge_of[p]=e; tail_s[p]=tl; }
}

// ---------------- E: per-wave softmax + aggregation + att write ----------------
__global__ __launch_bounds__(256) void k_agg3(const int* __restrict__ offs,
      const int* __restrict__ edge_of, const int* __restrict__ tail_s,
      const float* __restrict__ att_csr,
      const unsigned short* __restrict__ h_tail,
      float* __restrict__ att, float* __restrict__ out){
  int t = threadIdx.x;
  int l = t & 63;
  int i = blockIdx.x*4 + (t>>6);      // head node, grid = NH/4 exact
  int h = l & 7, hq = l >> 3;
  int s0 = offs[i];
  int deg = offs[i+1] - s0;

  // softmax stats (contiguous att_csr reads)
  float m = -1e30f;
  for (int q = hq; q < deg; q += 8) m = fmaxf(m, att_csr[(s0+q)*8 + h]);
  m = fmaxf(m, __shfl_xor(m, 8));
  m = fmaxf(m, __shfl_xor(m, 16));
  m = fmaxf(m, __shfl_xor(m, 32));
  float sum = 0.f;
  for (int q = hq; q < deg; q += 8) sum += __expf(att_csr[(s0+q)*8 + h] - m);
  sum += __shfl_xor(sum, 8); sum += __shfl_xor(sum, 16); sum += __shfl_xor(sum, 32);
  float r = (deg > 0) ? 1.f/sum : 0.f;

  float mh = __shfl(m, hq), rh = __shfl(r, hq);
  bool wlane = (l & 7) == 0;
  float acc[8];
#pragma unroll
  for (int c=0;c<8;c++) acc[c]=0.f;
  int j = 0;
  for (; j+4 <= deg; j += 4){
    int p0=s0+j, p1=p0+1, p2=p0+2, p3=p0+3;
    int t0=tail_s[p0], t1=tail_s[p1], t2=tail_s[p2], t3=tail_s[p3];
    float a0=att_csr[p0*8+hq], a1=att_csr[p1*8+hq];
    float a2=att_csr[p2*8+hq], a3=att_csr[p3*8+hq];
    uint4 r0 = *(const uint4*)(h_tail + (size_t)t0*512 + l*8);
    uint4 r1 = *(const uint4*)(h_tail + (size_t)t1*512 + l*8);
    uint4 r2 = *(const uint4*)(h_tail + (size_t)t2*512 + l*8);
    uint4 r3 = *(const uint4*)(h_tail + (size_t)t3*512 + l*8);
    float w0=__expf(a0-mh)*rh, w1=__expf(a1-mh)*rh;
    float w2=__expf(a2-mh)*rh, w3=__expf(a3-mh)*rh;
    if (wlane){
      __builtin_nontemporal_store(w0, &att[(size_t)edge_of[p0]*8 + hq]);
      __builtin_nontemporal_store(w1, &att[(size_t)edge_of[p1]*8 + hq]);
      __builtin_nontemporal_store(w2, &att[(size_t)edge_of[p2]*8 + hq]);
      __builtin_nontemporal_store(w3, &att[(size_t)edge_of[p3]*8 + hq]);
    }
    fma8(acc, w0, r0);
    fma8(acc, w1, r1);
    fma8(acc, w2, r2);
    fma8(acc, w3, r3);
  }
  for (; j < deg; j++){
    int p0 = s0+j;
    int t0 = tail_s[p0];
    float a0 = att_csr[p0*8 + hq];
    uint4 r0 = *(const uint4*)(h_tail + (size_t)t0*512 + l*8);
    float w0 = __expf(a0 - mh) * rh;
    if (wlane) __builtin_nontemporal_store(w0, &att[(size_t)edge_of[p0]*8 + hq]);
    fma8(acc, w0, r0);
  }
  float* o = out + (size_t)i*512 + l*8;
  f32x4 v0 = {acc[0],acc[1],acc[2],acc[3]};
  f32x4 v1 = {acc[4],acc[5],acc[6],acc[7]};
  __builtin_nontemporal_store(v0, (f32x4*)o);
  __builtin_nontemporal_store(v1, (f32x4*)(o+4));
}

extern "C" void kernel_launch(void* const* d_in, const int* in_sizes, int n_in,
                              void* d_out, int out_size, void* d_ws, size_t ws_size,
                              hipStream_t stream) {
  const float* head_f   = (const float*)d_in[0];
  const float* tail_f   = (const float*)d_in[1];
  const int*   head_ind = (const int*)d_in[2];
  const int*   tail_ind = (const int*)d_in[3];
  const int*   tmp_edge = (const int*)d_in[4];
  const float* edge_emb = (const float*)d_in[5];
  const float* W        = (const float*)d_in[6];
  const float* W_e      = (const float*)d_in[7];
  const float* a_l      = (const float*)d_in[8];
  const float* a_r      = (const float*)d_in[9];
  const float* a_e      = (const float*)d_in[10];

  float* out = (float*)d_out;
  float* att = out + (size_t)NH*512;
  // A_bf scratch lives in the `out` region (51.3 MB <= 102 MB); k_agg3 fully
  // overwrites `out` afterwards, so this is deterministic and ws stays small.
  unsigned short* A_bf = (unsigned short*)d_out;

  char* ws = (char*)d_ws;
  auto alloc = [&](size_t bytes)->char*{ char* p = ws; ws += (bytes+511)&~(size_t)511; return p; };
  unsigned short* Wt    = (unsigned short*)alloc((size_t)512*256*2);
  unsigned short* wlr_t = (unsigned short*)alloc((size_t)16*256*2);
  float* h_e            = (float*)alloc(512);
  float* h_l            = (float*)alloc((size_t)NH*8*4);
  float* h_r            = (float*)alloc((size_t)NT*8*4);
  unsigned short* h_tail= (unsigned short*)alloc((size_t)MPAD*512*2);
  int* cnt              = (int*)alloc((size_t)NH*4);
  int* offs             = (int*)alloc((size_t)(NH+1)*4);
  int* cur              = (int*)alloc((size_t)NH*4);
  int* edge_of          = (int*)alloc((size_t)NE*4);
  int* tail_s           = (int*)alloc((size_t)NE*4);
  float* att_csr        = (float*)alloc((size_t)NE*8*4);

  hipMemsetAsync(cnt, 0, (size_t)NH*4, stream);
  k_fuse1<<<16138,256,0,stream>>>(tail_f, A_bf, head_ind, cnt, W, Wt,
                                  W_e, edge_emb, a_l, a_r, a_e, wlr_t, h_e);
  k_fuse2<<<1+3128+196,256,0,stream>>>(A_bf, Wt, a_r, h_tail, h_r,
                                       head_f, wlr_t, h_l, cnt, offs, cur);
  k_logit2<<<NE*8/256,256,0,stream>>>(head_ind, tail_ind, tmp_edge, h_l, h_r, h_e,
                                      cur, att_csr, edge_of, tail_s);
  k_agg3<<<NH/4,256,0,stream>>>(offs, edge_of, tail_s, att_csr, h_tail, att, out);
}

// Round 15
// 412.382 us; speedup vs baseline: 2.5292x; 1.1794x over previous
//
#include <hip/hip_runtime.h>

#define NH 50000
#define NT 100000
#define NE 800000
#define MPAD 100096   // 782 * 128

typedef __attribute__((ext_vector_type(8))) short bf16x8;
typedef __attribute__((ext_vector_type(4))) float f32x4;
typedef __attribute__((ext_vector_type(8))) unsigned short u16x8;
typedef __attribute__((ext_vector_type(4))) unsigned int u32x4;

__device__ __forceinline__ unsigned short f2bf(float f){
  unsigned int u = __float_as_uint(f);
  u += 0x7FFFu + ((u >> 16) & 1u);
  return (unsigned short)(u >> 16);
}

__device__ __forceinline__ void fma8(float* acc, float w, uint4 pk){
  acc[0] += w*__uint_as_float(pk.x<<16); acc[1] += w*__uint_as_float(pk.x&0xFFFF0000u);
  acc[2] += w*__uint_as_float(pk.y<<16); acc[3] += w*__uint_as_float(pk.y&0xFFFF0000u);
  acc[4] += w*__uint_as_float(pk.z<<16); acc[5] += w*__uint_as_float(pk.z&0xFFFF0000u);
  acc[6] += w*__uint_as_float(pk.w<<16); acc[7] += w*__uint_as_float(pk.w&0xFFFF0000u);
}

// async 16B global -> LDS (linear dest = wave-uniform base + lane*16)
__device__ __forceinline__ void gl2lds16(const unsigned short* g, unsigned short* l){
  __builtin_amdgcn_global_load_lds(
      (const __attribute__((address_space(1))) void*)g,
      (__attribute__((address_space(3))) void*)l, 16, 0, 0);
}

// ================= F1: cvt || hist || wt || prep (independent, fused) =================
__global__ __launch_bounds__(256) void k_fuse1(
      const float* __restrict__ tail_f, unsigned short* __restrict__ A_bf,
      const int* __restrict__ head_ind, int* __restrict__ cnt,
      const float* __restrict__ W, unsigned short* __restrict__ Wt,
      const float* __restrict__ W_e, const float* __restrict__ edge_emb,
      const float* __restrict__ a_l, const float* __restrict__ a_r,
      const float* __restrict__ a_e,
      unsigned short* __restrict__ wlr_t, float* __restrict__ h_e){
  __shared__ float s_al[512], s_ar[512], s_ae[512], s_wef[512];
  int b = blockIdx.x, t = threadIdx.x;
  if (b < 12500){
    // ---- cvt: tail_feature fp32 -> bf16 [NT][256]
    size_t g = (size_t)b*256 + t;
    const float* src = tail_f + g*8;
    float4 v0 = *(const float4*)(src);
    float4 v1 = *(const float4*)(src + 4);
    u16x8 s;
    s[0]=f2bf(v0.x); s[1]=f2bf(v0.y); s[2]=f2bf(v0.z); s[3]=f2bf(v0.w);
    s[4]=f2bf(v1.x); s[5]=f2bf(v1.y); s[6]=f2bf(v1.z); s[7]=f2bf(v1.w);
    *(u16x8*)(A_bf + g*8) = s;
  } else if (b < 15625){
    // ---- hist
    int e = (b-12500)*256 + t;
    atomicAdd(&cnt[head_ind[e]], 1);
  } else if (b < 16137){
    // ---- wt: W transposed bf16 [512][256]
    int n = b - 15625, k = t;
    Wt[n*256+k] = f2bf(W[k*512+n]);
  } else {
    // ---- prep
    for (int i=t;i<512;i+=256){ s_al[i]=a_l[i]; s_ar[i]=a_r[i]; s_ae[i]=a_e[i]; }
    __syncthreads();
    { int k = t;
      for (int h=0;h<8;h++){
        float accl=0.f, accr=0.f;
        for (int d=0; d<64; d++){
          float w = W[k*512 + h*64 + d];
          accl += w*s_al[h*64+d];
          accr += w*s_ar[h*64+d];
        }
        wlr_t[h*256 + k]     = f2bf(accl);
        wlr_t[(8+h)*256 + k] = f2bf(accr);
      }
    }
    if (t<64){
      for (int h=0;h<8;h++){
        float acc=0.f;
        for (int f=0; f<64; f++) acc += W_e[t*512 + h*64 + f]*s_ae[h*64+f];
        s_wef[t*8+h]=acc;
      }
    }
    __syncthreads();
    if (t<40){
      int ty=t>>3, h=t&7;
      float acc=0.f;
      for (int k2=0;k2<64;k2++) acc += edge_emb[ty*64+k2]*s_wef[k2*8+h];
      h_e[t]=acc;
    }
  }
}

// ================= F2: hl (blocks 0..195, first) || gemm (196..3323) ==========
__device__ __forceinline__ void gemm3_body(unsigned short* smem, int bid,
      const unsigned short* __restrict__ A_bf, const unsigned short* __restrict__ Wt,
      const float* __restrict__ a_r_g, unsigned short* __restrict__ Cout,
      float* __restrict__ h_r){
  unsigned short* As0 = smem;          // 16 KB
  unsigned short* As1 = smem + 8192;   // 16 KB
  int t = threadIdx.x;
  int wave = t>>6, lane = t&63;
  int lr = lane & 15, lq = lane >> 4;

  // XCD-bijective + panel-grouped decode: 3128 = 8*391
  int wg  = (bid & 7)*391 + (bid >> 3);
  int m0 = (wg >> 2)*128;
  int n0 = (wg & 3)*128;
  int wm = (wave>>1)*64, wn = (wave&1)*64;

  f32x4 acc[4][4];
#pragma unroll
  for (int mf=0;mf<4;mf++)
#pragma unroll
    for (int nf=0;nf<4;nf++) acc[mf][nf] = (f32x4){0.f,0.f,0.f,0.f};

  bf16x8 b0[8], b1[8], b2[8], b3[8];

#define STAGEA(dst, kt) do { \
    _Pragma("unroll") \
    for (int i=0;i<4;i++){ \
      int v = wave*256 + i*64 + lane; \
      int row = v>>3, un = (v&7) ^ (row&7); \
      gl2lds16(A_bf + (size_t)(m0+row)*256 + (kt)*64 + un*8, \
               &(dst)[(wave*256 + i*64)*8]); \
    } } while(0)

#define LOADB(kt, bb) do { \
    _Pragma("unroll") \
    for (int ks=0;ks<2;ks++) \
      _Pragma("unroll") \
      for (int nf=0;nf<4;nf++){ \
        int c = wn + nf*16 + lr; \
        (bb)[ks*4+nf] = *(const bf16x8*)(Wt + (size_t)(n0+c)*256 + ((kt)*8+ks*4+lq)*8); \
      } } while(0)

#define COMPUTE(Asb, bb) do { \
    _Pragma("unroll") \
    for (int ks=0;ks<2;ks++){ \
      bf16x8 af[4]; \
      _Pragma("unroll") \
      for (int mf=0;mf<4;mf++){ \
        int r = wm + mf*16 + lr; \
        int u = (ks*4 + lq) ^ (r&7); \
        af[mf] = *(const bf16x8*)((const char*)(Asb) + r*128 + u*16); \
      } \
      _Pragma("unroll") \
      for (int mf=0;mf<4;mf++) \
        _Pragma("unroll") \
        for (int nf=0;nf<4;nf++) \
          acc[mf][nf] = __builtin_amdgcn_mfma_f32_16x16x32_bf16(af[mf], (bb)[ks*4+nf], acc[mf][nf], 0,0,0); \
    } } while(0)

#define WAITV(N) asm volatile("s_waitcnt vmcnt(" #N ")" ::: "memory")
#define RBAR() do { __builtin_amdgcn_s_barrier(); __builtin_amdgcn_sched_barrier(0); } while(0)

  STAGEA(As0, 0); LOADB(0, b0);
  STAGEA(As1, 1); LOADB(1, b1);
  WAITV(20); RBAR();
  COMPUTE(As0, b0);
  RBAR();
  STAGEA(As0, 2); LOADB(2, b2);
  WAITV(20); RBAR();
  COMPUTE(As1, b1);
  RBAR();
  STAGEA(As1, 3); LOADB(3, b3);
  WAITV(20); RBAR();
  COMPUTE(As0, b2);
  WAITV(8);  RBAR();
  COMPUTE(As1, b3);
#undef STAGEA
#undef LOADB
#undef COMPUTE
#undef WAITV
#undef RBAR

  // epilogue A: h_r[row, head] = sum_d a_r[h,d]*C_fp32[row, h*64+d]
  {
    int h = (n0 + wn) >> 6;
    float w[4];
#pragma unroll
    for (int nf=0;nf<4;nf++) w[nf] = a_r_g[h*64 + nf*16 + lr];
#pragma unroll
    for (int mf=0;mf<4;mf++)
#pragma unroll
      for (int j=0;j<4;j++){
        float s = acc[mf][0][j]*w[0] + acc[mf][1][j]*w[1]
                + acc[mf][2][j]*w[2] + acc[mf][3][j]*w[3];
        s += __shfl_xor(s, 1); s += __shfl_xor(s, 2);
        s += __shfl_xor(s, 4); s += __shfl_xor(s, 8);
        int gr = m0 + wm + mf*16 + lq*4 + j;
        if (lr == 0 && gr < NT) h_r[(size_t)gr*8 + h] = s;
      }
  }

  // epilogue B: coalesced C store via LDS (reuse smem as [128][256B], XOR bits 5-6)
  __syncthreads();
  unsigned short* Cs = smem;
#pragma unroll
  for (int mf=0;mf<4;mf++)
#pragma unroll
    for (int nf=0;nf<4;nf++)
#pragma unroll
      for (int j=0;j<4;j++){
        int row = wm + mf*16 + lq*4 + j;
        int cb  = (wn + nf*16 + lr)*2;
        *(unsigned short*)((char*)Cs + row*256 + (cb ^ ((row&12)<<3))) = f2bf(acc[mf][nf][j]);
      }
  __syncthreads();
#pragma unroll
  for (int i=0;i<8;i++){
    int v = i*256 + t;          // 16B unit id, 0..2047
    int row = v>>4, u = v&15;
    u32x4 val = *(const u32x4*)((const char*)Cs + row*256 + ((u*16) ^ ((row&12)<<3)));
    *(u32x4*)(Cout + (size_t)(m0+row)*512 + n0 + u*8) = val;
  }
}

__device__ __forceinline__ void hl_body(unsigned short* As, unsigned short* Bs, int bid,
      const float* __restrict__ head_f, const unsigned short* __restrict__ wlr_t,
      float* __restrict__ h_l){
  int t = threadIdx.x;
  int wave = t>>6, lane = t&63;
  int lr = lane&15, lq = lane>>4;
  long r0 = (long)bid*256;

#pragma unroll
  for (int i=0;i<2;i++){
    int q = i*256 + t;
    int c = q>>5, un = q&31;
    float4 v = *(const float4*)(wlr_t + c*256 + un*8);
    int u = un ^ (c&7);
    *(float4*)((char*)Bs + c*512 + u*16) = v;
  }

  f32x4 acc[4];
#pragma unroll
  for (int mf=0;mf<4;mf++) acc[mf]=(f32x4){0.f,0.f,0.f,0.f};

  for (int kt=0; kt<4; kt++){
    __syncthreads();
#pragma unroll
    for (int i=0;i<16;i++){
      int q = i*256+t;
      int row = q>>4, cg = q&15;
      long gr = r0 + row;
      float4 v = make_float4(0.f,0.f,0.f,0.f);
      if (gr < NH) v = *(const float4*)(head_f + gr*256 + kt*64 + cg*4);
      int u = (cg>>1) ^ (row&7);
      ushort4 sv;
      sv.x=f2bf(v.x); sv.y=f2bf(v.y); sv.z=f2bf(v.z); sv.w=f2bf(v.w);
      *(ushort4*)((char*)As + row*128 + u*16 + (cg&1)*8) = sv;
    }
    __syncthreads();
#pragma unroll
    for (int ks=0;ks<2;ks++){
      int un = kt*8 + ks*4 + lq;
      int cu = un ^ (lr&7);
      bf16x8 bfr = *(const bf16x8*)((const char*)Bs + lr*512 + cu*16);
#pragma unroll
      for (int mf=0;mf<4;mf++){
        int r = wave*64 + mf*16 + lr;
        int u = (ks*4+lq) ^ (r&7);
        bf16x8 afr = *(const bf16x8*)((const char*)As + r*128 + u*16);
        acc[mf] = __builtin_amdgcn_mfma_f32_16x16x32_bf16(afr, bfr, acc[mf], 0,0,0);
      }
    }
  }
#pragma unroll
  for (int mf=0;mf<4;mf++)
#pragma unroll
    for (int j=0;j<4;j++){
      long grow = r0 + wave*64 + mf*16 + lq*4 + j;
      if (grow < NH && lr < 8) h_l[grow*8+lr] = acc[mf][j];
    }
}

__global__ __launch_bounds__(256) void k_fuse2(
      const unsigned short* __restrict__ A_bf, const unsigned short* __restrict__ Wt,
      const float* __restrict__ a_r_g, unsigned short* __restrict__ Cout,
      float* __restrict__ h_r,
      const float* __restrict__ head_f, const unsigned short* __restrict__ wlr_t,
      float* __restrict__ h_l){
  __shared__ __align__(16) unsigned short smem[20480];   // 40 KB union
  if (blockIdx.x < 196)
    hl_body(smem, smem + 16384, blockIdx.x, head_f, wlr_t, h_l);
  else
    gemm3_body(smem, blockIdx.x - 196, A_bf, Wt, a_r_g, Cout, h_r);
}

// ---------------- scans: counts -> offsets (R12-proven) ----------------
__global__ void k_scan1(const int* __restrict__ cnt, int* __restrict__ bsum){
  __shared__ int s[256];
  int b=blockIdx.x, t=threadIdx.x, g=b*256+t;
  s[t] = (g<NH)? cnt[g] : 0;
  __syncthreads();
  for (int off=128; off>0; off>>=1){ if (t<off) s[t]+=s[t+off]; __syncthreads(); }
  if (t==0) bsum[b]=s[0];
}
__global__ void k_scan3(const int* __restrict__ cnt, const int* __restrict__ bsum,
                        int* __restrict__ offs, int* __restrict__ cur){
  __shared__ int s[256];
  __shared__ int sb[196];
  int b=blockIdx.x, t=threadIdx.x, g=b*256+t;
  if (t < 196) sb[t] = bsum[t];
  int v=(g<NH)? cnt[g] : 0;
  s[t]=v; __syncthreads();
  for (int off=1; off<256; off<<=1){
    int u=(t>=off)? s[t-off] : 0; __syncthreads();
    s[t]+=u; __syncthreads();
  }
  int base = 0;
  for (int j=0;j<b;j++) base += sb[j];
  int excl = s[t]-v + base;
  if (g<NH){
    offs[g]=excl; cur[g]=excl;
    if (g==NH-1) offs[NH]=excl+v;
  }
}

// ---------------- D1: logits + CSR scatter ----------------
__global__ void k_logit2(const int* __restrict__ head_ind, const int* __restrict__ tail_ind,
                         const int* __restrict__ tmp_edge,
                         const float* __restrict__ h_l, const float* __restrict__ h_r,
                         const float* __restrict__ h_e,
                         int* __restrict__ cur,
                         float* __restrict__ att_csr,
                         int* __restrict__ edge_of, int* __restrict__ tail_s){
  int g = blockIdx.x*256 + threadIdx.x;   // NE*8 threads exactly
  int e = g>>3, h = g&7, l = threadIdx.x&63;
  int hd = head_ind[e], tl = tail_ind[e], ty = tmp_edge[e];
  float v = h_l[hd*8+h] + h_r[(size_t)tl*8+h] + h_e[ty*8+h];
  v = v > 0.f ? v : 0.2f*v;
  int p = 0;
  if (h==0) p = atomicAdd(&cur[hd], 1);
  p = __shfl(p, l & ~7);
  att_csr[p*8+h] = v;
  if (h==0){ edge_of[p]=e; tail_s[p]=tl; }
}

// ---------------- E: per-wave softmax + aggregation + att write ----------------
__global__ __launch_bounds__(256) void k_agg3(const int* __restrict__ offs,
      const int* __restrict__ edge_of, const int* __restrict__ tail_s,
      const float* __restrict__ att_csr,
      const unsigned short* __restrict__ h_tail,
      float* __restrict__ att, float* __restrict__ out){
  int t = threadIdx.x;
  int l = t & 63;
  int i = blockIdx.x*4 + (t>>6);      // head node, grid = NH/4 exact
  int h = l & 7, hq = l >> 3;
  int s0 = offs[i];
  int deg = offs[i+1] - s0;

  // softmax stats (contiguous att_csr reads)
  float m = -1e30f;
  for (int q = hq; q < deg; q += 8) m = fmaxf(m, att_csr[(s0+q)*8 + h]);
  m = fmaxf(m, __shfl_xor(m, 8));
  m = fmaxf(m, __shfl_xor(m, 16));
  m = fmaxf(m, __shfl_xor(m, 32));
  float sum = 0.f;
  for (int q = hq; q < deg; q += 8) sum += __expf(att_csr[(s0+q)*8 + h] - m);
  sum += __shfl_xor(sum, 8); sum += __shfl_xor(sum, 16); sum += __shfl_xor(sum, 32);
  float r = (deg > 0) ? 1.f/sum : 0.f;

  float mh = __shfl(m, hq), rh = __shfl(r, hq);
  bool wlane = (l & 7) == 0;
  float acc[8];
#pragma unroll
  for (int c=0;c<8;c++) acc[c]=0.f;
  int j = 0;
  for (; j+4 <= deg; j += 4){
    int p0=s0+j, p1=p0+1, p2=p0+2, p3=p0+3;
    int t0=tail_s[p0], t1=tail_s[p1], t2=tail_s[p2], t3=tail_s[p3];
    float a0=att_csr[p0*8+hq], a1=att_csr[p1*8+hq];
    float a2=att_csr[p2*8+hq], a3=att_csr[p3*8+hq];
    uint4 r0 = *(const uint4*)(h_tail + (size_t)t0*512 + l*8);
    uint4 r1 = *(const uint4*)(h_tail + (size_t)t1*512 + l*8);
    uint4 r2 = *(const uint4*)(h_tail + (size_t)t2*512 + l*8);
    uint4 r3 = *(const uint4*)(h_tail + (size_t)t3*512 + l*8);
    float w0=__expf(a0-mh)*rh, w1=__expf(a1-mh)*rh;
    float w2=__expf(a2-mh)*rh, w3=__expf(a3-mh)*rh;
    if (wlane){
      __builtin_nontemporal_store(w0, &att[(size_t)edge_of[p0]*8 + hq]);
      __builtin_nontemporal_store(w1, &att[(size_t)edge_of[p1]*8 + hq]);
      __builtin_nontemporal_store(w2, &att[(size_t)edge_of[p2]*8 + hq]);
      __builtin_nontemporal_store(w3, &att[(size_t)edge_of[p3]*8 + hq]);
    }
    fma8(acc, w0, r0);
    fma8(acc, w1, r1);
    fma8(acc, w2, r2);
    fma8(acc, w3, r3);
  }
  for (; j < deg; j++){
    int p0 = s0+j;
    int t0 = tail_s[p0];
    float a0 = att_csr[p0*8 + hq];
    uint4 r0 = *(const uint4*)(h_tail + (size_t)t0*512 + l*8);
    float w0 = __expf(a0 - mh) * rh;
    if (wlane) __builtin_nontemporal_store(w0, &att[(size_t)edge_of[p0]*8 + hq]);
    fma8(acc, w0, r0);
  }
  float* o = out + (size_t)i*512 + l*8;
  f32x4 v0 = {acc[0],acc[1],acc[2],acc[3]};
  f32x4 v1 = {acc[4],acc[5],acc[6],acc[7]};
  __builtin_nontemporal_store(v0, (f32x4*)o);
  __builtin_nontemporal_store(v1, (f32x4*)(o+4));
}

extern "C" void kernel_launch(void* const* d_in, const int* in_sizes, int n_in,
                              void* d_out, int out_size, void* d_ws, size_t ws_size,
                              hipStream_t stream) {
  const float* head_f   = (const float*)d_in[0];
  const float* tail_f   = (const float*)d_in[1];
  const int*   head_ind = (const int*)d_in[2];
  const int*   tail_ind = (const int*)d_in[3];
  const int*   tmp_edge = (const int*)d_in[4];
  const float* edge_emb = (const float*)d_in[5];
  const float* W        = (const float*)d_in[6];
  const float* W_e      = (const float*)d_in[7];
  const float* a_l      = (const float*)d_in[8];
  const float* a_r      = (const float*)d_in[9];
  const float* a_e      = (const float*)d_in[10];

  float* out = (float*)d_out;
  float* att = out + (size_t)NH*512;
  // A_bf scratch lives in the `out` region (51.3 MB <= 102 MB); k_agg3 fully
  // overwrites `out` afterwards, so this is deterministic and ws stays small.
  unsigned short* A_bf = (unsigned short*)d_out;

  char* ws = (char*)d_ws;
  auto alloc = [&](size_t bytes)->char*{ char* p = ws; ws += (bytes+511)&~(size_t)511; return p; };
  unsigned short* Wt    = (unsigned short*)alloc((size_t)512*256*2);
  unsigned short* wlr_t = (unsigned short*)alloc((size_t)16*256*2);
  float* h_e            = (float*)alloc(512);
  float* h_l            = (float*)alloc((size_t)NH*8*4);
  float* h_r            = (float*)alloc((size_t)NT*8*4);
  unsigned short* h_tail= (unsigned short*)alloc((size_t)MPAD*512*2);
  int* cnt              = (int*)alloc((size_t)NH*4);
  int* offs             = (int*)alloc((size_t)(NH+1)*4);
  int* cur              = (int*)alloc((size_t)NH*4);
  int* bsum             = (int*)alloc(1024);
  int* edge_of          = (int*)alloc((size_t)NE*4);
  int* tail_s           = (int*)alloc((size_t)NE*4);
  float* att_csr        = (float*)alloc((size_t)NE*8*4);

  hipMemsetAsync(cnt, 0, (size_t)NH*4, stream);
  k_fuse1<<<16138,256,0,stream>>>(tail_f, A_bf, head_ind, cnt, W, Wt,
                                  W_e, edge_emb, a_l, a_r, a_e, wlr_t, h_e);
  k_scan1<<<196,256,0,stream>>>(cnt, bsum);
  k_fuse2<<<196+3128,256,0,stream>>>(A_bf, Wt, a_r, h_tail, h_r, head_f, wlr_t, h_l);
  k_scan3<<<196,256,0,stream>>>(cnt, bsum, offs, cur);
  k_logit2<<<NE*8/256,256,0,stream>>>(head_ind, tail_ind, tmp_edge, h_l, h_r, h_e,
                                      cur, att_csr, edge_of, tail_s);
  k_agg3<<<NH/4,256,0,stream>>>(offs, edge_of, tail_s, att_csr, h_tail, att, out);
}

// Round 16
// 405.223 us; speedup vs baseline: 2.5739x; 1.0177x over previous
//
#include <hip/hip_runtime.h>

#define NH 50000
#define NT 100000
#define NE 800000
#define MPAD 100096   // 782 * 128

typedef __attribute__((ext_vector_type(8))) short bf16x8;
typedef __attribute__((ext_vector_type(4))) float f32x4;
typedef __attribute__((ext_vector_type(8))) unsigned short u16x8;
typedef __attribute__((ext_vector_type(4))) unsigned int u32x4;

__device__ __forceinline__ unsigned short f2bf(float f){
  unsigned int u = __float_as_uint(f);
  u += 0x7FFFu + ((u >> 16) & 1u);
  return (unsigned short)(u >> 16);
}

__device__ __forceinline__ void fma8(float* acc, float w, uint4 pk){
  acc[0] += w*__uint_as_float(pk.x<<16); acc[1] += w*__uint_as_float(pk.x&0xFFFF0000u);
  acc[2] += w*__uint_as_float(pk.y<<16); acc[3] += w*__uint_as_float(pk.y&0xFFFF0000u);
  acc[4] += w*__uint_as_float(pk.z<<16); acc[5] += w*__uint_as_float(pk.z&0xFFFF0000u);
  acc[6] += w*__uint_as_float(pk.w<<16); acc[7] += w*__uint_as_float(pk.w&0xFFFF0000u);
}

// async 16B global -> LDS (linear dest = wave-uniform base + lane*16)
__device__ __forceinline__ void gl2lds16(const unsigned short* g, unsigned short* l){
  __builtin_amdgcn_global_load_lds(
      (const __attribute__((address_space(1))) void*)g,
      (__attribute__((address_space(3))) void*)l, 16, 0, 0);
}

// ================= F1: cvt || hist || wt || prep (independent, fused) =================
__global__ __launch_bounds__(256) void k_fuse1(
      const float* __restrict__ tail_f, unsigned short* __restrict__ A_bf,
      const int* __restrict__ head_ind, int* __restrict__ cnt,
      const float* __restrict__ W, unsigned short* __restrict__ Wt,
      const float* __restrict__ W_e, const float* __restrict__ edge_emb,
      const float* __restrict__ a_l, const float* __restrict__ a_r,
      const float* __restrict__ a_e,
      unsigned short* __restrict__ wlr_t, float* __restrict__ h_e){
  __shared__ float s_al[512], s_ar[512], s_ae[512], s_wef[512];
  int b = blockIdx.x, t = threadIdx.x;
  if (b < 12500){
    // ---- cvt: tail_feature fp32 -> bf16 [NT][256]
    size_t g = (size_t)b*256 + t;
    const float* src = tail_f + g*8;
    float4 v0 = *(const float4*)(src);
    float4 v1 = *(const float4*)(src + 4);
    u16x8 s;
    s[0]=f2bf(v0.x); s[1]=f2bf(v0.y); s[2]=f2bf(v0.z); s[3]=f2bf(v0.w);
    s[4]=f2bf(v1.x); s[5]=f2bf(v1.y); s[6]=f2bf(v1.z); s[7]=f2bf(v1.w);
    *(u16x8*)(A_bf + g*8) = s;
  } else if (b < 15625){
    // ---- hist
    int e = (b-12500)*256 + t;
    atomicAdd(&cnt[head_ind[e]], 1);
  } else if (b < 16137){
    // ---- wt: W transposed bf16 [512][256]
    int n = b - 15625, k = t;
    Wt[n*256+k] = f2bf(W[k*512+n]);
  } else {
    // ---- prep
    for (int i=t;i<512;i+=256){ s_al[i]=a_l[i]; s_ar[i]=a_r[i]; s_ae[i]=a_e[i]; }
    __syncthreads();
    { int k = t;
      for (int h=0;h<8;h++){
        float accl=0.f, accr=0.f;
        for (int d=0; d<64; d++){
          float w = W[k*512 + h*64 + d];
          accl += w*s_al[h*64+d];
          accr += w*s_ar[h*64+d];
        }
        wlr_t[h*256 + k]     = f2bf(accl);
        wlr_t[(8+h)*256 + k] = f2bf(accr);
      }
    }
    if (t<64){
      for (int h=0;h<8;h++){
        float acc=0.f;
        for (int f=0; f<64; f++) acc += W_e[t*512 + h*64 + f]*s_ae[h*64+f];
        s_wef[t*8+h]=acc;
      }
    }
    __syncthreads();
    if (t<40){
      int ty=t>>3, h=t&7;
      float acc=0.f;
      for (int k2=0;k2<64;k2++) acc += edge_emb[ty*64+k2]*s_wef[k2*8+h];
      h_e[t]=acc;
    }
  }
}

// ================= F2: hl (blocks 0..195, first) || gemm (196..3323) ==========
__device__ __forceinline__ void gemm3_body(unsigned short* smem, int bid,
      const unsigned short* __restrict__ A_bf, const unsigned short* __restrict__ Wt,
      const float* __restrict__ a_r_g, unsigned short* __restrict__ Cout,
      float* __restrict__ h_r){
  unsigned short* As0 = smem;          // 16 KB
  unsigned short* As1 = smem + 8192;   // 16 KB
  int t = threadIdx.x;
  int wave = t>>6, lane = t&63;
  int lr = lane & 15, lq = lane >> 4;

  // XCD-bijective + panel-grouped decode: 3128 = 8*391
  int wg  = (bid & 7)*391 + (bid >> 3);
  int m0 = (wg >> 2)*128;
  int n0 = (wg & 3)*128;
  int wm = (wave>>1)*64, wn = (wave&1)*64;

  f32x4 acc[4][4];
#pragma unroll
  for (int mf=0;mf<4;mf++)
#pragma unroll
    for (int nf=0;nf<4;nf++) acc[mf][nf] = (f32x4){0.f,0.f,0.f,0.f};

  bf16x8 b0[8], b1[8], b2[8], b3[8];

#define STAGEA(dst, kt) do { \
    _Pragma("unroll") \
    for (int i=0;i<4;i++){ \
      int v = wave*256 + i*64 + lane; \
      int row = v>>3, un = (v&7) ^ (row&7); \
      gl2lds16(A_bf + (size_t)(m0+row)*256 + (kt)*64 + un*8, \
               &(dst)[(wave*256 + i*64)*8]); \
    } } while(0)

#define LOADB(kt, bb) do { \
    _Pragma("unroll") \
    for (int ks=0;ks<2;ks++) \
      _Pragma("unroll") \
      for (int nf=0;nf<4;nf++){ \
        int c = wn + nf*16 + lr; \
        (bb)[ks*4+nf] = *(const bf16x8*)(Wt + (size_t)(n0+c)*256 + ((kt)*8+ks*4+lq)*8); \
      } } while(0)

#define COMPUTE(Asb, bb) do { \
    _Pragma("unroll") \
    for (int ks=0;ks<2;ks++){ \
      bf16x8 af[4]; \
      _Pragma("unroll") \
      for (int mf=0;mf<4;mf++){ \
        int r = wm + mf*16 + lr; \
        int u = (ks*4 + lq) ^ (r&7); \
        af[mf] = *(const bf16x8*)((const char*)(Asb) + r*128 + u*16); \
      } \
      _Pragma("unroll") \
      for (int mf=0;mf<4;mf++) \
        _Pragma("unroll") \
        for (int nf=0;nf<4;nf++) \
          acc[mf][nf] = __builtin_amdgcn_mfma_f32_16x16x32_bf16(af[mf], (bb)[ks*4+nf], acc[mf][nf], 0,0,0); \
    } } while(0)

#define WAITV(N) asm volatile("s_waitcnt vmcnt(" #N ")" ::: "memory")
#define RBAR() do { __builtin_amdgcn_s_barrier(); __builtin_amdgcn_sched_barrier(0); } while(0)

  STAGEA(As0, 0); LOADB(0, b0);
  STAGEA(As1, 1); LOADB(1, b1);
  WAITV(20); RBAR();
  COMPUTE(As0, b0);
  RBAR();
  STAGEA(As0, 2); LOADB(2, b2);
  WAITV(20); RBAR();
  COMPUTE(As1, b1);
  RBAR();
  STAGEA(As1, 3); LOADB(3, b3);
  WAITV(20); RBAR();
  COMPUTE(As0, b2);
  WAITV(8);  RBAR();
  COMPUTE(As1, b3);
#undef STAGEA
#undef LOADB
#undef COMPUTE
#undef WAITV
#undef RBAR

  // epilogue A: h_r[row, head] = sum_d a_r[h,d]*C_fp32[row, h*64+d]
  {
    int h = (n0 + wn) >> 6;
    float w[4];
#pragma unroll
    for (int nf=0;nf<4;nf++) w[nf] = a_r_g[h*64 + nf*16 + lr];
#pragma unroll
    for (int mf=0;mf<4;mf++)
#pragma unroll
      for (int j=0;j<4;j++){
        float s = acc[mf][0][j]*w[0] + acc[mf][1][j]*w[1]
                + acc[mf][2][j]*w[2] + acc[mf][3][j]*w[3];
        s += __shfl_xor(s, 1); s += __shfl_xor(s, 2);
        s += __shfl_xor(s, 4); s += __shfl_xor(s, 8);
        int gr = m0 + wm + mf*16 + lq*4 + j;
        if (lr == 0 && gr < NT) h_r[(size_t)gr*8 + h] = s;
      }
  }

  // epilogue B: coalesced C store via LDS (reuse smem as [128][256B], XOR bits 5-6)
  __syncthreads();
  unsigned short* Cs = smem;
#pragma unroll
  for (int mf=0;mf<4;mf++)
#pragma unroll
    for (int nf=0;nf<4;nf++)
#pragma unroll
      for (int j=0;j<4;j++){
        int row = wm + mf*16 + lq*4 + j;
        int cb  = (wn + nf*16 + lr)*2;
        *(unsigned short*)((char*)Cs + row*256 + (cb ^ ((row&12)<<3))) = f2bf(acc[mf][nf][j]);
      }
  __syncthreads();
#pragma unroll
  for (int i=0;i<8;i++){
    int v = i*256 + t;          // 16B unit id, 0..2047
    int row = v>>4, u = v&15;
    u32x4 val = *(const u32x4*)((const char*)Cs + row*256 + ((u*16) ^ ((row&12)<<3)));
    *(u32x4*)(Cout + (size_t)(m0+row)*512 + n0 + u*8) = val;
  }
}

__device__ __forceinline__ void hl_body(unsigned short* As, unsigned short* Bs, int bid,
      const float* __restrict__ head_f, const unsigned short* __restrict__ wlr_t,
      float* __restrict__ h_l){
  int t = threadIdx.x;
  int wave = t>>6, lane = t&63;
  int lr = lane&15, lq = lane>>4;
  long r0 = (long)bid*256;

#pragma unroll
  for (int i=0;i<2;i++){
    int q = i*256 + t;
    int c = q>>5, un = q&31;
    float4 v = *(const float4*)(wlr_t + c*256 + un*8);
    int u = un ^ (c&7);
    *(float4*)((char*)Bs + c*512 + u*16) = v;
  }

  f32x4 acc[4];
#pragma unroll
  for (int mf=0;mf<4;mf++) acc[mf]=(f32x4){0.f,0.f,0.f,0.f};

  for (int kt=0; kt<4; kt++){
    __syncthreads();
#pragma unroll
    for (int i=0;i<16;i++){
      int q = i*256+t;
      int row = q>>4, cg = q&15;
      long gr = r0 + row;
      float4 v = make_float4(0.f,0.f,0.f,0.f);
      if (gr < NH) v = *(const float4*)(head_f + gr*256 + kt*64 + cg*4);
      int u = (cg>>1) ^ (row&7);
      ushort4 sv;
      sv.x=f2bf(v.x); sv.y=f2bf(v.y); sv.z=f2bf(v.z); sv.w=f2bf(v.w);
      *(ushort4*)((char*)As + row*128 + u*16 + (cg&1)*8) = sv;
    }
    __syncthreads();
#pragma unroll
    for (int ks=0;ks<2;ks++){
      int un = kt*8 + ks*4 + lq;
      int cu = un ^ (lr&7);
      bf16x8 bfr = *(const bf16x8*)((const char*)Bs + lr*512 + cu*16);
#pragma unroll
      for (int mf=0;mf<4;mf++){
        int r = wave*64 + mf*16 + lr;
        int u = (ks*4+lq) ^ (r&7);
        bf16x8 afr = *(const bf16x8*)((const char*)As + r*128 + u*16);
        acc[mf] = __builtin_amdgcn_mfma_f32_16x16x32_bf16(afr, bfr, acc[mf], 0,0,0);
      }
    }
  }
#pragma unroll
  for (int mf=0;mf<4;mf++)
#pragma unroll
    for (int j=0;j<4;j++){
      long grow = r0 + wave*64 + mf*16 + lq*4 + j;
      if (grow < NH && lr < 8) h_l[grow*8+lr] = acc[mf][j];
    }
}

__global__ __launch_bounds__(256) void k_fuse2(
      const unsigned short* __restrict__ A_bf, const unsigned short* __restrict__ Wt,
      const float* __restrict__ a_r_g, unsigned short* __restrict__ Cout,
      float* __restrict__ h_r,
      const float* __restrict__ head_f, const unsigned short* __restrict__ wlr_t,
      float* __restrict__ h_l){
  __shared__ __align__(16) unsigned short smem[20480];   // 40 KB union
  if (blockIdx.x < 196)
    hl_body(smem, smem + 16384, blockIdx.x, head_f, wlr_t, h_l);
  else
    gemm3_body(smem, blockIdx.x - 196, A_bf, Wt, a_r_g, Cout, h_r);
}

// ---------------- scans: counts -> offsets (R12-proven) ----------------
__global__ void k_scan1(const int* __restrict__ cnt, int* __restrict__ bsum){
  __shared__ int s[256];
  int b=blockIdx.x, t=threadIdx.x, g=b*256+t;
  s[t] = (g<NH)? cnt[g] : 0;
  __syncthreads();
  for (int off=128; off>0; off>>=1){ if (t<off) s[t]+=s[t+off]; __syncthreads(); }
  if (t==0) bsum[b]=s[0];
}
__global__ void k_scan3(const int* __restrict__ cnt, const int* __restrict__ bsum,
                        int* __restrict__ offs, int* __restrict__ cur){
  __shared__ int s[256];
  __shared__ int sb[196];
  int b=blockIdx.x, t=threadIdx.x, g=b*256+t;
  if (t < 196) sb[t] = bsum[t];
  int v=(g<NH)? cnt[g] : 0;
  s[t]=v; __syncthreads();
  for (int off=1; off<256; off<<=1){
    int u=(t>=off)? s[t-off] : 0; __syncthreads();
    s[t]+=u; __syncthreads();
  }
  int base = 0;
  for (int j=0;j<b;j++) base += sb[j];
  int excl = s[t]-v + base;
  if (g<NH){
    offs[g]=excl; cur[g]=excl;
    if (g==NH-1) offs[NH]=excl+v;
  }
}

// ---------------- D1: logits + CSR scatter ----------------
__global__ void k_logit2(const int* __restrict__ head_ind, const int* __restrict__ tail_ind,
                         const int* __restrict__ tmp_edge,
                         const float* __restrict__ h_l, const float* __restrict__ h_r,
                         const float* __restrict__ h_e,
                         int* __restrict__ cur,
                         float* __restrict__ att_csr,
                         int* __restrict__ edge_of, int* __restrict__ tail_s){
  int g = blockIdx.x*256 + threadIdx.x;   // NE*8 threads exactly
  int e = g>>3, h = g&7, l = threadIdx.x&63;
  int hd = head_ind[e], tl = tail_ind[e], ty = tmp_edge[e];
  float v = h_l[hd*8+h] + h_r[(size_t)tl*8+h] + h_e[ty*8+h];
  v = v > 0.f ? v : 0.2f*v;
  int p = 0;
  if (h==0) p = atomicAdd(&cur[hd], 1);
  p = __shfl(p, l & ~7);
  att_csr[p*8+h] = v;
  if (h==0){ edge_of[p]=e; tail_s[p]=tl; }
}

// ---------------- E: per-wave softmax + 2-pass tail-blocked aggregation ----------------
__global__ __launch_bounds__(256) void k_agg3(const int* __restrict__ offs,
      const int* __restrict__ edge_of, const int* __restrict__ tail_s,
      const float* __restrict__ att_csr,
      const unsigned short* __restrict__ h_tail,
      float* __restrict__ att, float* __restrict__ out){
  int t = threadIdx.x;
  int l = t & 63;
  int i = blockIdx.x*4 + (t>>6);      // head node, grid = NH/4 exact
  int h = l & 7, hq = l >> 3;
  int s0 = offs[i];
  int deg = offs[i+1] - s0;

  // softmax stats (contiguous att_csr reads)
  float m = -1e30f;
  for (int q = hq; q < deg; q += 8) m = fmaxf(m, att_csr[(s0+q)*8 + h]);
  m = fmaxf(m, __shfl_xor(m, 8));
  m = fmaxf(m, __shfl_xor(m, 16));
  m = fmaxf(m, __shfl_xor(m, 32));
  float sum = 0.f;
  for (int q = hq; q < deg; q += 8) sum += __expf(att_csr[(s0+q)*8 + h] - m);
  sum += __shfl_xor(sum, 8); sum += __shfl_xor(sum, 16); sum += __shfl_xor(sum, 32);
  float r = (deg > 0) ? 1.f/sum : 0.f;

  float mh = __shfl(m, hq), rh = __shfl(r, hq);
  bool wlane = (l & 7) == 0;
  float acc[8];
#pragma unroll
  for (int c=0;c<8;c++) acc[c]=0.f;

  // 2-pass tail-range blocking: pass 0 -> tails [0,50000), pass 1 -> [50000,100000)
  // keeps the per-pass gather footprint (50 MB) L3-resident; bucket test is
  // wave-uniform (all 64 lanes share the edge), so no divergence.
#pragma unroll
  for (int pass=0; pass<2; pass++){
    int lo = pass*50000;
    int j = 0;
    for (; j+4 <= deg; j += 4){
      int p0=s0+j, p1=p0+1, p2=p0+2, p3=p0+3;
      int t0=tail_s[p0], t1=tail_s[p1], t2=tail_s[p2], t3=tail_s[p3];
      float a0=att_csr[p0*8+hq], a1=att_csr[p1*8+hq];
      float a2=att_csr[p2*8+hq], a3=att_csr[p3*8+hq];
      float w0=__expf(a0-mh)*rh, w1=__expf(a1-mh)*rh;
      float w2=__expf(a2-mh)*rh, w3=__expf(a3-mh)*rh;
      if (pass==0 && wlane){
        __builtin_nontemporal_store(w0, &att[(size_t)edge_of[p0]*8 + hq]);
        __builtin_nontemporal_store(w1, &att[(size_t)edge_of[p1]*8 + hq]);
        __builtin_nontemporal_store(w2, &att[(size_t)edge_of[p2]*8 + hq]);
        __builtin_nontemporal_store(w3, &att[(size_t)edge_of[p3]*8 + hq]);
      }
      bool b0 = (unsigned)(t0-lo) < 50000u;
      bool b1 = (unsigned)(t1-lo) < 50000u;
      bool b2 = (unsigned)(t2-lo) < 50000u;
      bool b3 = (unsigned)(t3-lo) < 50000u;
      uint4 r0, r1, r2, r3;
      if (b0) r0 = *(const uint4*)(h_tail + (size_t)t0*512 + l*8);
      if (b1) r1 = *(const uint4*)(h_tail + (size_t)t1*512 + l*8);
      if (b2) r2 = *(const uint4*)(h_tail + (size_t)t2*512 + l*8);
      if (b3) r3 = *(const uint4*)(h_tail + (size_t)t3*512 + l*8);
      if (b0) fma8(acc, w0, r0);
      if (b1) fma8(acc, w1, r1);
      if (b2) fma8(acc, w2, r2);
      if (b3) fma8(acc, w3, r3);
    }
    for (; j < deg; j++){
      int p0 = s0+j;
      int t0 = tail_s[p0];
      float a0 = att_csr[p0*8 + hq];
      float w0 = __expf(a0 - mh) * rh;
      if (pass==0 && wlane)
        __builtin_nontemporal_store(w0, &att[(size_t)edge_of[p0]*8 + hq]);
      if ((unsigned)(t0-lo) < 50000u){
        uint4 r0 = *(const uint4*)(h_tail + (size_t)t0*512 + l*8);
        fma8(acc, w0, r0);
      }
    }
  }
  float* o = out + (size_t)i*512 + l*8;
  f32x4 v0 = {acc[0],acc[1],acc[2],acc[3]};
  f32x4 v1 = {acc[4],acc[5],acc[6],acc[7]};
  __builtin_nontemporal_store(v0, (f32x4*)o);
  __builtin_nontemporal_store(v1, (f32x4*)(o+4));
}

extern "C" void kernel_launch(void* const* d_in, const int* in_sizes, int n_in,
                              void* d_out, int out_size, void* d_ws, size_t ws_size,
                              hipStream_t stream) {
  const float* head_f   = (const float*)d_in[0];
  const float* tail_f   = (const float*)d_in[1];
  const int*   head_ind = (const int*)d_in[2];
  const int*   tail_ind = (const int*)d_in[3];
  const int*   tmp_edge = (const int*)d_in[4];
  const float* edge_emb = (const float*)d_in[5];
  const float* W        = (const float*)d_in[6];
  const float* W_e      = (const float*)d_in[7];
  const float* a_l      = (const float*)d_in[8];
  const float* a_r      = (const float*)d_in[9];
  const float* a_e      = (const float*)d_in[10];

  float* out = (float*)d_out;
  float* att = out + (size_t)NH*512;
  // A_bf scratch lives in the `out` region (51.3 MB <= 102 MB); k_agg3 fully
  // overwrites `out` afterwards, so this is deterministic and ws stays small.
  unsigned short* A_bf = (unsigned short*)d_out;

  char* ws = (char*)d_ws;
  auto alloc = [&](size_t bytes)->char*{ char* p = ws; ws += (bytes+511)&~(size_t)511; return p; };
  unsigned short* Wt    = (unsigned short*)alloc((size_t)512*256*2);
  unsigned short* wlr_t = (unsigned short*)alloc((size_t)16*256*2);
  float* h_e            = (float*)alloc(512);
  float* h_l            = (float*)alloc((size_t)NH*8*4);
  float* h_r            = (float*)alloc((size_t)NT*8*4);
  unsigned short* h_tail= (unsigned short*)alloc((size_t)MPAD*512*2);
  int* cnt              = (int*)alloc((size_t)NH*4);
  int* offs             = (int*)alloc((size_t)(NH+1)*4);
  int* cur              = (int*)alloc((size_t)NH*4);
  int* bsum             = (int*)alloc(1024);
  int* edge_of          = (int*)alloc((size_t)NE*4);
  int* tail_s           = (int*)alloc((size_t)NE*4);
  float* att_csr        = (float*)alloc((size_t)NE*8*4);

  hipMemsetAsync(cnt, 0, (size_t)NH*4, stream);
  k_fuse1<<<16138,256,0,stream>>>(tail_f, A_bf, head_ind, cnt, W, Wt,
                                  W_e, edge_emb, a_l, a_r, a_e, wlr_t, h_e);
  k_scan1<<<196,256,0,stream>>>(cnt, bsum);
  k_fuse2<<<196+3128,256,0,stream>>>(A_bf, Wt, a_r, h_tail, h_r, head_f, wlr_t, h_l);
  k_scan3<<<196,256,0,stream>>>(cnt, bsum, offs, cur);
  k_logit2<<<NE*8/256,256,0,stream>>>(head_ind, tail_ind, tmp_edge, h_l, h_r, h_e,
                                      cur, att_csr, edge_of, tail_s);
  k_agg3<<<NH/4,256,0,stream>>>(offs, edge_of, tail_s, att_csr, h_tail, att, out);
}

// Round 17
// 393.038 us; speedup vs baseline: 2.6537x; 1.0310x over previous
//
#include <hip/hip_runtime.h>

#define NH 50000
#define NT 100000
#define NE 800000
#define MPAD 100096   // 782 * 128

typedef __attribute__((ext_vector_type(8))) short bf16x8;
typedef __attribute__((ext_vector_type(4))) float f32x4;
typedef __attribute__((ext_vector_type(8))) unsigned short u16x8;
typedef __attribute__((ext_vector_type(4))) unsigned int u32x4;

__device__ __forceinline__ unsigned short f2bf(float f){
  unsigned int u = __float_as_uint(f);
  u += 0x7FFFu + ((u >> 16) & 1u);
  return (unsigned short)(u >> 16);
}

__device__ __forceinline__ void fma8(float* acc, float w, uint4 pk){
  acc[0] += w*__uint_as_float(pk.x<<16); acc[1] += w*__uint_as_float(pk.x&0xFFFF0000u);
  acc[2] += w*__uint_as_float(pk.y<<16); acc[3] += w*__uint_as_float(pk.y&0xFFFF0000u);
  acc[4] += w*__uint_as_float(pk.z<<16); acc[5] += w*__uint_as_float(pk.z&0xFFFF0000u);
  acc[6] += w*__uint_as_float(pk.w<<16); acc[7] += w*__uint_as_float(pk.w&0xFFFF0000u);
}

// async 16B global -> LDS (linear dest = wave-uniform base + lane*16)
__device__ __forceinline__ void gl2lds16(const unsigned short* g, unsigned short* l){
  __builtin_amdgcn_global_load_lds(
      (const __attribute__((address_space(1))) void*)g,
      (__attribute__((address_space(3))) void*)l, 16, 0, 0);
}

// ================= F1: cvt || hist || wt || prep (independent, fused) =================
__global__ __launch_bounds__(256) void k_fuse1(
      const float* __restrict__ tail_f, unsigned short* __restrict__ A_bf,
      const int* __restrict__ head_ind, int* __restrict__ cnt,
      const float* __restrict__ W, unsigned short* __restrict__ Wt,
      const float* __restrict__ W_e, const float* __restrict__ edge_emb,
      const float* __restrict__ a_l, const float* __restrict__ a_r,
      const float* __restrict__ a_e,
      unsigned short* __restrict__ wlr_t, float* __restrict__ h_e){
  __shared__ float s_al[512], s_ar[512], s_ae[512], s_wef[512];
  int b = blockIdx.x, t = threadIdx.x;
  if (b < 12500){
    // ---- cvt: tail_feature fp32 -> bf16 [NT][256]
    size_t g = (size_t)b*256 + t;
    const float* src = tail_f + g*8;
    float4 v0 = *(const float4*)(src);
    float4 v1 = *(const float4*)(src + 4);
    u16x8 s;
    s[0]=f2bf(v0.x); s[1]=f2bf(v0.y); s[2]=f2bf(v0.z); s[3]=f2bf(v0.w);
    s[4]=f2bf(v1.x); s[5]=f2bf(v1.y); s[6]=f2bf(v1.z); s[7]=f2bf(v1.w);
    *(u16x8*)(A_bf + g*8) = s;
  } else if (b < 15625){
    // ---- hist
    int e = (b-12500)*256 + t;
    atomicAdd(&cnt[head_ind[e]], 1);
  } else if (b < 16137){
    // ---- wt: W transposed bf16 [512][256]
    int n = b - 15625, k = t;
    Wt[n*256+k] = f2bf(W[k*512+n]);
  } else {
    // ---- prep
    for (int i=t;i<512;i+=256){ s_al[i]=a_l[i]; s_ar[i]=a_r[i]; s_ae[i]=a_e[i]; }
    __syncthreads();
    { int k = t;
      for (int h=0;h<8;h++){
        float accl=0.f, accr=0.f;
        for (int d=0; d<64; d++){
          float w = W[k*512 + h*64 + d];
          accl += w*s_al[h*64+d];
          accr += w*s_ar[h*64+d];
        }
        wlr_t[h*256 + k]     = f2bf(accl);
        wlr_t[(8+h)*256 + k] = f2bf(accr);
      }
    }
    if (t<64){
      for (int h=0;h<8;h++){
        float acc=0.f;
        for (int f=0; f<64; f++) acc += W_e[t*512 + h*64 + f]*s_ae[h*64+f];
        s_wef[t*8+h]=acc;
      }
    }
    __syncthreads();
    if (t<40){
      int ty=t>>3, h=t&7;
      float acc=0.f;
      for (int k2=0;k2<64;k2++) acc += edge_emb[ty*64+k2]*s_wef[k2*8+h];
      h_e[t]=acc;
    }
  }
}

// ================= F2: hl (blocks 0..195, first) || gemm (196..3323) ==========
__device__ __forceinline__ void gemm3_body(unsigned short* smem, int bid,
      const unsigned short* __restrict__ A_bf, const unsigned short* __restrict__ Wt,
      const float* __restrict__ a_r_g, unsigned short* __restrict__ Cout,
      float* __restrict__ h_r){
  unsigned short* As0 = smem;          // 16 KB
  unsigned short* As1 = smem + 8192;   // 16 KB
  int t = threadIdx.x;
  int wave = t>>6, lane = t&63;
  int lr = lane & 15, lq = lane >> 4;

  // XCD-bijective + panel-grouped decode: 3128 = 8*391
  int wg  = (bid & 7)*391 + (bid >> 3);
  int m0 = (wg >> 2)*128;
  int n0 = (wg & 3)*128;
  int wm = (wave>>1)*64, wn = (wave&1)*64;

  f32x4 acc[4][4];
#pragma unroll
  for (int mf=0;mf<4;mf++)
#pragma unroll
    for (int nf=0;nf<4;nf++) acc[mf][nf] = (f32x4){0.f,0.f,0.f,0.f};

  bf16x8 b0[8], b1[8], b2[8], b3[8];

#define STAGEA(dst, kt) do { \
    _Pragma("unroll") \
    for (int i=0;i<4;i++){ \
      int v = wave*256 + i*64 + lane; \
      int row = v>>3, un = (v&7) ^ (row&7); \
      gl2lds16(A_bf + (size_t)(m0+row)*256 + (kt)*64 + un*8, \
               &(dst)[(wave*256 + i*64)*8]); \
    } } while(0)

#define LOADB(kt, bb) do { \
    _Pragma("unroll") \
    for (int ks=0;ks<2;ks++) \
      _Pragma("unroll") \
      for (int nf=0;nf<4;nf++){ \
        int c = wn + nf*16 + lr; \
        (bb)[ks*4+nf] = *(const bf16x8*)(Wt + (size_t)(n0+c)*256 + ((kt)*8+ks*4+lq)*8); \
      } } while(0)

#define COMPUTE(Asb, bb) do { \
    _Pragma("unroll") \
    for (int ks=0;ks<2;ks++){ \
      bf16x8 af[4]; \
      _Pragma("unroll") \
      for (int mf=0;mf<4;mf++){ \
        int r = wm + mf*16 + lr; \
        int u = (ks*4 + lq) ^ (r&7); \
        af[mf] = *(const bf16x8*)((const char*)(Asb) + r*128 + u*16); \
      } \
      _Pragma("unroll") \
      for (int mf=0;mf<4;mf++) \
        _Pragma("unroll") \
        for (int nf=0;nf<4;nf++) \
          acc[mf][nf] = __builtin_amdgcn_mfma_f32_16x16x32_bf16(af[mf], (bb)[ks*4+nf], acc[mf][nf], 0,0,0); \
    } } while(0)

#define WAITV(N) asm volatile("s_waitcnt vmcnt(" #N ")" ::: "memory")
#define RBAR() do { __builtin_amdgcn_s_barrier(); __builtin_amdgcn_sched_barrier(0); } while(0)

  STAGEA(As0, 0); LOADB(0, b0);
  STAGEA(As1, 1); LOADB(1, b1);
  WAITV(20); RBAR();
  COMPUTE(As0, b0);
  RBAR();
  STAGEA(As0, 2); LOADB(2, b2);
  WAITV(20); RBAR();
  COMPUTE(As1, b1);
  RBAR();
  STAGEA(As1, 3); LOADB(3, b3);
  WAITV(20); RBAR();
  COMPUTE(As0, b2);
  WAITV(8);  RBAR();
  COMPUTE(As1, b3);
#undef STAGEA
#undef LOADB
#undef COMPUTE
#undef WAITV
#undef RBAR

  // epilogue A: h_r[row, head] = sum_d a_r[h,d]*C_fp32[row, h*64+d]
  {
    int h = (n0 + wn) >> 6;
    float w[4];
#pragma unroll
    for (int nf=0;nf<4;nf++) w[nf] = a_r_g[h*64 + nf*16 + lr];
#pragma unroll
    for (int mf=0;mf<4;mf++)
#pragma unroll
      for (int j=0;j<4;j++){
        float s = acc[mf][0][j]*w[0] + acc[mf][1][j]*w[1]
                + acc[mf][2][j]*w[2] + acc[mf][3][j]*w[3];
        s += __shfl_xor(s, 1); s += __shfl_xor(s, 2);
        s += __shfl_xor(s, 4); s += __shfl_xor(s, 8);
        int gr = m0 + wm + mf*16 + lq*4 + j;
        if (lr == 0 && gr < NT) h_r[(size_t)gr*8 + h] = s;
      }
  }

  // epilogue B: coalesced C store via LDS (reuse smem as [128][256B], XOR bits 5-6)
  __syncthreads();
  unsigned short* Cs = smem;
#pragma unroll
  for (int mf=0;mf<4;mf++)
#pragma unroll
    for (int nf=0;nf<4;nf++)
#pragma unroll
      for (int j=0;j<4;j++){
        int row = wm + mf*16 + lq*4 + j;
        int cb  = (wn + nf*16 + lr)*2;
        *(unsigned short*)((char*)Cs + row*256 + (cb ^ ((row&12)<<3))) = f2bf(acc[mf][nf][j]);
      }
  __syncthreads();
#pragma unroll
  for (int i=0;i<8;i++){
    int v = i*256 + t;          // 16B unit id, 0..2047
    int row = v>>4, u = v&15;
    u32x4 val = *(const u32x4*)((const char*)Cs + row*256 + ((u*16) ^ ((row&12)<<3)));
    *(u32x4*)(Cout + (size_t)(m0+row)*512 + n0 + u*8) = val;
  }
}

__device__ __forceinline__ void hl_body(unsigned short* As, unsigned short* Bs, int bid,
      const float* __restrict__ head_f, const unsigned short* __restrict__ wlr_t,
      float* __restrict__ h_l){
  int t = threadIdx.x;
  int wave = t>>6, lane = t&63;
  int lr = lane&15, lq = lane>>4;
  long r0 = (long)bid*256;

#pragma unroll
  for (int i=0;i<2;i++){
    int q = i*256 + t;
    int c = q>>5, un = q&31;
    float4 v = *(const float4*)(wlr_t + c*256 + un*8);
    int u = un ^ (c&7);
    *(float4*)((char*)Bs + c*512 + u*16) = v;
  }

  f32x4 acc[4];
#pragma unroll
  for (int mf=0;mf<4;mf++) acc[mf]=(f32x4){0.f,0.f,0.f,0.f};

  for (int kt=0; kt<4; kt++){
    __syncthreads();
#pragma unroll
    for (int i=0;i<16;i++){
      int q = i*256+t;
      int row = q>>4, cg = q&15;
      long gr = r0 + row;
      float4 v = make_float4(0.f,0.f,0.f,0.f);
      if (gr < NH) v = *(const float4*)(head_f + gr*256 + kt*64 + cg*4);
      int u = (cg>>1) ^ (row&7);
      ushort4 sv;
      sv.x=f2bf(v.x); sv.y=f2bf(v.y); sv.z=f2bf(v.z); sv.w=f2bf(v.w);
      *(ushort4*)((char*)As + row*128 + u*16 + (cg&1)*8) = sv;
    }
    __syncthreads();
#pragma unroll
    for (int ks=0;ks<2;ks++){
      int un = kt*8 + ks*4 + lq;
      int cu = un ^ (lr&7);
      bf16x8 bfr = *(const bf16x8*)((const char*)Bs + lr*512 + cu*16);
#pragma unroll
      for (int mf=0;mf<4;mf++){
        int r = wave*64 + mf*16 + lr;
        int u = (ks*4+lq) ^ (r&7);
        bf16x8 afr = *(const bf16x8*)((const char*)As + r*128 + u*16);
        acc[mf] = __builtin_amdgcn_mfma_f32_16x16x32_bf16(afr, bfr, acc[mf], 0,0,0);
      }
    }
  }
#pragma unroll
  for (int mf=0;mf<4;mf++)
#pragma unroll
    for (int j=0;j<4;j++){
      long grow = r0 + wave*64 + mf*16 + lq*4 + j;
      if (grow < NH && lr < 8) h_l[grow*8+lr] = acc[mf][j];
    }
}

__global__ __launch_bounds__(256) void k_fuse2(
      const unsigned short* __restrict__ A_bf, const unsigned short* __restrict__ Wt,
      const float* __restrict__ a_r_g, unsigned short* __restrict__ Cout,
      float* __restrict__ h_r,
      const float* __restrict__ head_f, const unsigned short* __restrict__ wlr_t,
      float* __restrict__ h_l){
  __shared__ __align__(16) unsigned short smem[20480];   // 40 KB union
  if (blockIdx.x < 196)
    hl_body(smem, smem + 16384, blockIdx.x, head_f, wlr_t, h_l);
  else
    gemm3_body(smem, blockIdx.x - 196, A_bf, Wt, a_r_g, Cout, h_r);
}

// ---------------- scans: counts -> offsets (R12-proven) ----------------
__global__ void k_scan1(const int* __restrict__ cnt, int* __restrict__ bsum){
  __shared__ int s[256];
  int b=blockIdx.x, t=threadIdx.x, g=b*256+t;
  s[t] = (g<NH)? cnt[g] : 0;
  __syncthreads();
  for (int off=128; off>0; off>>=1){ if (t<off) s[t]+=s[t+off]; __syncthreads(); }
  if (t==0) bsum[b]=s[0];
}
__global__ void k_scan3(const int* __restrict__ cnt, const int* __restrict__ bsum,
                        int* __restrict__ offs, int* __restrict__ cur){
  __shared__ int s[256];
  __shared__ int sb[196];
  int b=blockIdx.x, t=threadIdx.x, g=b*256+t;
  if (t < 196) sb[t] = bsum[t];
  int v=(g<NH)? cnt[g] : 0;
  s[t]=v; __syncthreads();
  for (int off=1; off<256; off<<=1){
    int u=(t>=off)? s[t-off] : 0; __syncthreads();
    s[t]+=u; __syncthreads();
  }
  int base = 0;
  for (int j=0;j<b;j++) base += sb[j];
  int excl = s[t]-v + base;
  if (g<NH){
    offs[g]=excl; cur[g]=excl;
    if (g==NH-1) offs[NH]=excl+v;
  }
}

// ---------------- D1: logits + CSR scatter, one thread per edge ----------------
__global__ __launch_bounds__(256) void k_logit3(
      const int* __restrict__ head_ind, const int* __restrict__ tail_ind,
      const int* __restrict__ tmp_edge,
      const float* __restrict__ h_l, const float* __restrict__ h_r,
      const float* __restrict__ h_e,
      int* __restrict__ cur,
      float* __restrict__ att_csr,
      int* __restrict__ edge_of, int* __restrict__ tail_s){
  int e = blockIdx.x*256 + threadIdx.x;   // NE threads exactly
  int hd = head_ind[e], tl = tail_ind[e], ty = tmp_edge[e];
  float4 l0 = *(const float4*)(h_l + (size_t)hd*8);
  float4 l1 = *(const float4*)(h_l + (size_t)hd*8 + 4);
  float4 r0 = *(const float4*)(h_r + (size_t)tl*8);
  float4 r1 = *(const float4*)(h_r + (size_t)tl*8 + 4);
  float4 e0 = *(const float4*)(h_e + ty*8);
  float4 e1 = *(const float4*)(h_e + ty*8 + 4);
  f32x4 v0, v1;
  v0[0]=l0.x+r0.x+e0.x; v0[1]=l0.y+r0.y+e0.y; v0[2]=l0.z+r0.z+e0.z; v0[3]=l0.w+r0.w+e0.w;
  v1[0]=l1.x+r1.x+e1.x; v1[1]=l1.y+r1.y+e1.y; v1[2]=l1.z+r1.z+e1.z; v1[3]=l1.w+r1.w+e1.w;
#pragma unroll
  for (int c=0;c<4;c++){
    v0[c] = v0[c] > 0.f ? v0[c] : 0.2f*v0[c];
    v1[c] = v1[c] > 0.f ? v1[c] : 0.2f*v1[c];
  }
  int p = atomicAdd(&cur[hd], 1);
  *(f32x4*)(att_csr + (size_t)p*8)     = v0;
  *(f32x4*)(att_csr + (size_t)p*8 + 4) = v1;
  edge_of[p]=e; tail_s[p]=tl;
}

// ---------------- E: per-wave softmax + aggregation + att write (R12-proven) ----------------
__global__ __launch_bounds__(256) void k_agg3(const int* __restrict__ offs,
      const int* __restrict__ edge_of, const int* __restrict__ tail_s,
      const float* __restrict__ att_csr,
      const unsigned short* __restrict__ h_tail,
      float* __restrict__ att, float* __restrict__ out){
  int t = threadIdx.x;
  int l = t & 63;
  int i = blockIdx.x*4 + (t>>6);      // head node, grid = NH/4 exact
  int h = l & 7, hq = l >> 3;
  int s0 = offs[i];
  int deg = offs[i+1] - s0;

  // softmax stats (contiguous att_csr reads)
  float m = -1e30f;
  for (int q = hq; q < deg; q += 8) m = fmaxf(m, att_csr[(s0+q)*8 + h]);
  m = fmaxf(m, __shfl_xor(m, 8));
  m = fmaxf(m, __shfl_xor(m, 16));
  m = fmaxf(m, __shfl_xor(m, 32));
  float sum = 0.f;
  for (int q = hq; q < deg; q += 8) sum += __expf(att_csr[(s0+q)*8 + h] - m);
  sum += __shfl_xor(sum, 8); sum += __shfl_xor(sum, 16); sum += __shfl_xor(sum, 32);
  float r = (deg > 0) ? 1.f/sum : 0.f;

  float mh = __shfl(m, hq), rh = __shfl(r, hq);
  bool wlane = (l & 7) == 0;
  float acc[8];
#pragma unroll
  for (int c=0;c<8;c++) acc[c]=0.f;
  int j = 0;
  for (; j+4 <= deg; j += 4){
    int p0=s0+j, p1=p0+1, p2=p0+2, p3=p0+3;
    int t0=tail_s[p0], t1=tail_s[p1], t2=tail_s[p2], t3=tail_s[p3];
    float a0=att_csr[p0*8+hq], a1=att_csr[p1*8+hq];
    float a2=att_csr[p2*8+hq], a3=att_csr[p3*8+hq];
    uint4 r0 = *(const uint4*)(h_tail + (size_t)t0*512 + l*8);
    uint4 r1 = *(const uint4*)(h_tail + (size_t)t1*512 + l*8);
    uint4 r2 = *(const uint4*)(h_tail + (size_t)t2*512 + l*8);
    uint4 r3 = *(const uint4*)(h_tail + (size_t)t3*512 + l*8);
    float w0=__expf(a0-mh)*rh, w1=__expf(a1-mh)*rh;
    float w2=__expf(a2-mh)*rh, w3=__expf(a3-mh)*rh;
    if (wlane){
      __builtin_nontemporal_store(w0, &att[(size_t)edge_of[p0]*8 + hq]);
      __builtin_nontemporal_store(w1, &att[(size_t)edge_of[p1]*8 + hq]);
      __builtin_nontemporal_store(w2, &att[(size_t)edge_of[p2]*8 + hq]);
      __builtin_nontemporal_store(w3, &att[(size_t)edge_of[p3]*8 + hq]);
    }
    fma8(acc, w0, r0);
    fma8(acc, w1, r1);
    fma8(acc, w2, r2);
    fma8(acc, w3, r3);
  }
  for (; j < deg; j++){
    int p0 = s0+j;
    int t0 = tail_s[p0];
    float a0 = att_csr[p0*8 + hq];
    uint4 r0 = *(const uint4*)(h_tail + (size_t)t0*512 + l*8);
    float w0 = __expf(a0 - mh) * rh;
    if (wlane) __builtin_nontemporal_store(w0, &att[(size_t)edge_of[p0]*8 + hq]);
    fma8(acc, w0, r0);
  }
  float* o = out + (size_t)i*512 + l*8;
  f32x4 v0 = {acc[0],acc[1],acc[2],acc[3]};
  f32x4 v1 = {acc[4],acc[5],acc[6],acc[7]};
  __builtin_nontemporal_store(v0, (f32x4*)o);
  __builtin_nontemporal_store(v1, (f32x4*)(o+4));
}

extern "C" void kernel_launch(void* const* d_in, const int* in_sizes, int n_in,
                              void* d_out, int out_size, void* d_ws, size_t ws_size,
                              hipStream_t stream) {
  const float* head_f   = (const float*)d_in[0];
  const float* tail_f   = (const float*)d_in[1];
  const int*   head_ind = (const int*)d_in[2];
  const int*   tail_ind = (const int*)d_in[3];
  const int*   tmp_edge = (const int*)d_in[4];
  const float* edge_emb = (const float*)d_in[5];
  const float* W        = (const float*)d_in[6];
  const float* W_e      = (const float*)d_in[7];
  const float* a_l      = (const float*)d_in[8];
  const float* a_r      = (const float*)d_in[9];
  const float* a_e      = (const float*)d_in[10];

  float* out = (float*)d_out;
  float* att = out + (size_t)NH*512;
  // A_bf scratch lives in the `out` region (51.3 MB <= 102 MB); k_agg3 fully
  // overwrites `out` afterwards, so this is deterministic and ws stays small.
  unsigned short* A_bf = (unsigned short*)d_out;

  char* ws = (char*)d_ws;
  auto alloc = [&](size_t bytes)->char*{ char* p = ws; ws += (bytes+511)&~(size_t)511; return p; };
  unsigned short* Wt    = (unsigned short*)alloc((size_t)512*256*2);
  unsigned short* wlr_t = (unsigned short*)alloc((size_t)16*256*2);
  float* h_e            = (float*)alloc(512);
  float* h_l            = (float*)alloc((size_t)NH*8*4);
  float* h_r            = (float*)alloc((size_t)NT*8*4);
  unsigned short* h_tail= (unsigned short*)alloc((size_t)MPAD*512*2);
  int* cnt              = (int*)alloc((size_t)NH*4);
  int* offs             = (int*)alloc((size_t)(NH+1)*4);
  int* cur              = (int*)alloc((size_t)NH*4);
  int* bsum             = (int*)alloc(1024);
  int* edge_of          = (int*)alloc((size_t)NE*4);
  int* tail_s           = (int*)alloc((size_t)NE*4);
  float* att_csr        = (float*)alloc((size_t)NE*8*4);

  hipMemsetAsync(cnt, 0, (size_t)NH*4, stream);
  k_fuse1<<<16138,256,0,stream>>>(tail_f, A_bf, head_ind, cnt, W, Wt,
                                  W_e, edge_emb, a_l, a_r, a_e, wlr_t, h_e);
  k_scan1<<<196,256,0,stream>>>(cnt, bsum);
  k_fuse2<<<196+3128,256,0,stream>>>(A_bf, Wt, a_r, h_tail, h_r, head_f, wlr_t, h_l);
  k_scan3<<<196,256,0,stream>>>(cnt, bsum, offs, cur);
  k_logit3<<<NE/256,256,0,stream>>>(head_ind, tail_ind, tmp_edge, h_l, h_r, h_e,
                                    cur, att_csr, edge_of, tail_s);
  k_agg3<<<NH/4,256,0,stream>>>(offs, edge_of, tail_s, att_csr, h_tail, att, out);
}